// Round 1
// baseline (9979.716 us; speedup 1.0000x reference)
//
#include <hip/hip_runtime.h>
#include <hip/hip_bf16.h>
#include <math.h>

#define BB 8
#define WW 256
#define FF 16
#define DD 128
#define HH 8
#define NTOK (BB*WW*FF)        // 32768
#define SCALE 0.08838834764831845f
#define INV_D (1.0f/128.0f)
#define LN10K_D 0.07195578415606394f   // ln(10000)/128

typedef __hip_bfloat16 bf16;

__device__ __forceinline__ float bf2f(bf16 x){ return __bfloat162float(x); }
__device__ __forceinline__ bf16 f2bf(float x){ return __float2bfloat16(x); }

// ---------------------------------------------------------------------------
// Kernel 1: causal convs + stack + @w_val + bias + sinusoidal PE  -> h [B,W,F,D]
// grid = B*W blocks, 256 threads
// ---------------------------------------------------------------------------
__global__ __launch_bounds__(256) void embed_kernel(
    const float* __restrict__ x,
    const float* __restrict__ w1, const float* __restrict__ b1,
    const float* __restrict__ w2, const float* __restrict__ b2,
    const float* __restrict__ w3, const float* __restrict__ b3,
    const float* __restrict__ wval, const float* __restrict__ bval,
    float* __restrict__ h)
{
    int bw = blockIdx.x;               // b*W + w
    int b = bw >> 8, w = bw & 255;
    int tid = threadIdx.x;
    __shared__ float s[FF][4];
    if (tid < 64) {
        int f = tid >> 2, t = tid & 3;
        const float* xb = x + (size_t)b*WW*FF + f;   // stride FF over time
        float v;
        if (t == 0) {
            v = xb[(size_t)w*FF];
        } else if (t == 1) {
            float acc = b1[f];
            #pragma unroll
            for (int kk = 0; kk < 4; kk++) { int t0 = w - (3-kk); if (t0 >= 0) acc += w1[f*4+kk]*xb[(size_t)t0*FF]; }
            v = acc;
        } else if (t == 2) {
            float acc = b2[f];
            #pragma unroll
            for (int kk = 0; kk < 8; kk++) { int t0 = w - (7-kk)*2; if (t0 >= 0) acc += w2[f*8+kk]*xb[(size_t)t0*FF]; }
            v = acc;
        } else {
            float acc = b3[f];
            #pragma unroll
            for (int kk = 0; kk < 16; kk++) { int t0 = w - (15-kk)*3; if (t0 >= 0) acc += w3[f*16+kk]*xb[(size_t)t0*FF]; }
            v = acc;
        }
        s[f][t] = v;
    }
    __syncthreads();
    #pragma unroll
    for (int r = 0; r < 8; r++) {
        int lin = r*256 + tid;
        int f = lin >> 7, d = lin & 127;
        float div = expf(-(float)(d & ~1) * LN10K_D);
        float arg = (float)w * div;
        float pe = (d & 1) ? cosf(arg) : sinf(arg);
        float e = bval[d] + pe;
        #pragma unroll
        for (int t = 0; t < 4; t++) e += s[f][t]*wval[t*128 + d];
        h[((size_t)bw*FF + f)*128 + d] = e;
    }
}

// ---------------------------------------------------------------------------
// Kernel 2: fused LayerNorm + QKV GEMM.  A = LN(h) [32 tok x 128], B = w_qkv
// chunk [128 x 128 of 3072].  q scaled by SCALE.  Outputs bf16.
// grid = (numTok/32, 24), 256 threads, 4x4 micro-tile
// ---------------------------------------------------------------------------
__global__ __launch_bounds__(256) void qkv_kernel(
    const float* __restrict__ h, const float* __restrict__ wq,
    const float* __restrict__ g, const float* __restrict__ bln,
    bf16* __restrict__ q, bf16* __restrict__ k, bf16* __restrict__ v,
    int tokbase)
{
    __shared__ __align__(16) float As[32][128];
    __shared__ __align__(16) float Bs[32][128];
    __shared__ float red[32][8][2];
    int tid = threadIdx.x;
    int tl0 = blockIdx.x * 32;
    int n0  = blockIdx.y * 128;

    // ---- stage A with LN (8 threads/row, 16 floats each) ----
    {
        int row = tid >> 3, l8 = tid & 7;
        const float* hr = h + ((size_t)(tokbase + tl0 + row))*128 + l8*16;
        float xv[16];
        float s1 = 0.f, s2 = 0.f;
        #pragma unroll
        for (int j = 0; j < 16; j++) { xv[j] = hr[j]; s1 += xv[j]; s2 += xv[j]*xv[j]; }
        red[row][l8][0] = s1; red[row][l8][1] = s2;
        __syncthreads();
        float m = 0.f, sq = 0.f;
        #pragma unroll
        for (int j = 0; j < 8; j++) { m += red[row][j][0]; sq += red[row][j][1]; }
        m *= INV_D; sq = sq*INV_D - m*m;
        float rs = rsqrtf(sq + 1e-5f);
        #pragma unroll
        for (int j = 0; j < 16; j++) {
            int d = l8*16 + j;
            As[row][d] = (xv[j]-m)*rs*g[d] + bln[d];
        }
    }

    float acc[4][4] = {};
    int tm = tid >> 5, tn = tid & 31;
    for (int kc = 0; kc < 4; kc++) {
        __syncthreads();
        #pragma unroll
        for (int i = 0; i < 4; i++) {            // stage B chunk [32 x 128]
            int lin = i*256 + tid;               // float4 units
            int kk = lin >> 5, nn = (lin & 31)*4;
            *(float4*)&Bs[kk][nn] = *(const float4*)(wq + (size_t)(kc*32+kk)*3072 + n0 + nn);
        }
        __syncthreads();
        #pragma unroll
        for (int kk = 0; kk < 32; kk++) {
            float a0 = As[tm*4+0][kc*32+kk];
            float a1 = As[tm*4+1][kc*32+kk];
            float a2 = As[tm*4+2][kc*32+kk];
            float a3 = As[tm*4+3][kc*32+kk];
            float4 bv = *(const float4*)&Bs[kk][tn*4];
            acc[0][0] += a0*bv.x; acc[0][1] += a0*bv.y; acc[0][2] += a0*bv.z; acc[0][3] += a0*bv.w;
            acc[1][0] += a1*bv.x; acc[1][1] += a1*bv.y; acc[1][2] += a1*bv.z; acc[1][3] += a1*bv.w;
            acc[2][0] += a2*bv.x; acc[2][1] += a2*bv.y; acc[2][2] += a2*bv.z; acc[2][3] += a2*bv.w;
            acc[3][0] += a3*bv.x; acc[3][1] += a3*bv.y; acc[3][2] += a3*bv.z; acc[3][3] += a3*bv.w;
        }
    }

    bf16* dst; int nrel; float scl;
    if (n0 < 1024)      { dst = q; nrel = n0;        scl = SCALE; }
    else if (n0 < 2048) { dst = k; nrel = n0 - 1024; scl = 1.0f; }
    else                { dst = v; nrel = n0 - 2048; scl = 1.0f; }
    #pragma unroll
    for (int ii = 0; ii < 4; ii++) {
        size_t rb = (size_t)(tl0 + tm*4 + ii)*1024 + nrel + tn*4;
        #pragma unroll
        for (int jj = 0; jj < 4; jj++) dst[rb + jj] = f2bf(acc[ii][jj]*scl);
    }
}

// ---------------------------------------------------------------------------
// Kernel 3: variable attention (attend over F=16 per (b,w,h)). Writes o.
// grid = nbl*W*H, 256 threads
// ---------------------------------------------------------------------------
__global__ __launch_bounds__(256) void vattn_kernel(
    const bf16* __restrict__ q, const bf16* __restrict__ k, const bf16* __restrict__ v,
    bf16* __restrict__ o)
{
    int bx = blockIdx.x;
    int hh = bx & 7; int bw = bx >> 3;       // local b*W + w
    int tid = threadIdx.x;
    __shared__ float qs[16][129];
    __shared__ float ks[16][129];
    __shared__ float vs[16][129];
    __shared__ float S[16][17];
    __shared__ float rsum[16];
    #pragma unroll
    for (int r = 0; r < 8; r++) {
        int lin = r*256 + tid;
        int f = lin >> 7, d = lin & 127;
        size_t idx = ((size_t)bw*FF + f)*1024 + hh*128 + d;
        qs[f][d] = bf2f(q[idx]);
        ks[f][d] = bf2f(k[idx]);
        vs[f][d] = bf2f(v[idx]);
    }
    __syncthreads();
    int i = tid >> 4, j = tid & 15;
    float s = 0.f;
    #pragma unroll 16
    for (int d = 0; d < 128; d++) s += qs[i][d]*ks[j][d];
    S[i][j] = s;
    __syncthreads();
    float m = -INFINITY;
    #pragma unroll
    for (int jj = 0; jj < 16; jj++) m = fmaxf(m, S[i][jj]);
    float p = __expf(s - m);
    __syncthreads();
    S[i][j] = p;
    __syncthreads();
    if (j == 0) {
        float sm = 0.f;
        #pragma unroll
        for (int jj = 0; jj < 16; jj++) sm += S[i][jj];
        rsum[i] = sm;
    }
    __syncthreads();
    float inv = 1.f / rsum[i];
    float acc[8] = {};
    int dbase = j;
    #pragma unroll
    for (int jj = 0; jj < 16; jj++) {
        float pj = S[i][jj];
        #pragma unroll
        for (int r = 0; r < 8; r++) acc[r] += pj * vs[jj][dbase + 16*r];
    }
    size_t ob = ((size_t)bw*FF + i)*1024 + hh*128;
    #pragma unroll
    for (int r = 0; r < 8; r++) o[ob + dbase + 16*r] = f2bf(acc[r]*inv);
}

// ---------------------------------------------------------------------------
// Kernel 4: temporal attention (attend over W=256 per (b,f,h)). o += result.
// grid = nbl*F*H*16 (16-row i-tiles), 256 threads
// ---------------------------------------------------------------------------
__global__ __launch_bounds__(256) void tattn_kernel(
    const bf16* __restrict__ q, const bf16* __restrict__ k, const bf16* __restrict__ v,
    bf16* __restrict__ o)
{
    int bx = blockIdx.x;
    int it = bx & 15; int hh = (bx >> 4) & 7; int f = (bx >> 7) & 15; int bl = bx >> 11;
    int i0 = it*16;
    int tid = threadIdx.x;
    __shared__ float qs[16][129];
    __shared__ float kv[32][129];
    __shared__ float S[16][257];
    __shared__ float red[16][17];

    #pragma unroll
    for (int r = 0; r < 8; r++) {
        int lin = r*256 + tid;
        int i = lin >> 7, d = lin & 127;
        size_t idx = ((size_t)((bl*WW + i0 + i)*FF + f))*1024 + hh*128 + d;
        qs[i][d] = bf2f(q[idx]);
    }
    int i = tid >> 4, l = tid & 15;

    // phase 1: scores S[i][j] for all 256 j
    for (int jt = 0; jt < 8; jt++) {
        __syncthreads();
        #pragma unroll
        for (int r = 0; r < 16; r++) {
            int lin = r*256 + tid;
            int jj = lin >> 7, d = lin & 127;
            size_t idx = ((size_t)((bl*WW + jt*32 + jj)*FF + f))*1024 + hh*128 + d;
            kv[jj][d] = bf2f(k[idx]);
        }
        __syncthreads();
        float s0 = 0.f, s1 = 0.f;
        #pragma unroll 16
        for (int d = 0; d < 128; d++) {
            float qv = qs[i][d];
            s0 += qv * kv[l][d];
            s1 += qv * kv[l+16][d];
        }
        S[i][jt*32 + l]      = s0;
        S[i][jt*32 + l + 16] = s1;
    }
    __syncthreads();

    // phase 2: softmax (thread owns j = l + 16m)
    float pm = -INFINITY;
    #pragma unroll
    for (int m = 0; m < 16; m++) pm = fmaxf(pm, S[i][l + 16*m]);
    red[i][l] = pm;
    __syncthreads();
    float rm = -INFINITY;
    #pragma unroll
    for (int jj = 0; jj < 16; jj++) rm = fmaxf(rm, red[i][jj]);
    float ps = 0.f;
    #pragma unroll
    for (int m = 0; m < 16; m++) {
        float e = __expf(S[i][l + 16*m] - rm);
        S[i][l + 16*m] = e;
        ps += e;
    }
    __syncthreads();
    red[i][l] = ps;
    __syncthreads();
    float rs = 0.f;
    #pragma unroll
    for (int jj = 0; jj < 16; jj++) rs += red[i][jj];
    float inv = 1.f / rs;

    // phase 3: P @ V
    float acc[8] = {};
    int dbase = l;
    for (int jt = 0; jt < 8; jt++) {
        __syncthreads();
        #pragma unroll
        for (int r = 0; r < 16; r++) {
            int lin = r*256 + tid;
            int jj = lin >> 7, d = lin & 127;
            size_t idx = ((size_t)((bl*WW + jt*32 + jj)*FF + f))*1024 + hh*128 + d;
            kv[jj][d] = bf2f(v[idx]);
        }
        __syncthreads();
        #pragma unroll 8
        for (int jj = 0; jj < 32; jj++) {
            float p = S[i][jt*32 + jj];
            #pragma unroll
            for (int r = 0; r < 8; r++) acc[r] += p * kv[jj][dbase + 16*r];
        }
    }
    size_t ob = ((size_t)((bl*WW + i0 + i)*FF + f))*1024 + hh*128;
    #pragma unroll
    for (int r = 0; r < 8; r++) {
        size_t idx = ob + dbase + 16*r;
        o[idx] = f2bf(bf2f(o[idx]) + acc[r]*inv);
    }
}

// ---------------------------------------------------------------------------
// Kernel 5: out-projection + bias + residual into h.
// o [ntok x 1024] bf16 @ w_out [1024 x 128] fp32.  grid = numTok/32, 256 thr
// ---------------------------------------------------------------------------
__global__ __launch_bounds__(256) void proj_kernel(
    const bf16* __restrict__ o, const float* __restrict__ wo, const float* __restrict__ bo,
    float* __restrict__ h, int tokbase)
{
    __shared__ __align__(16) float As[32][33];
    __shared__ __align__(16) float Bs[32][128];
    int tid = threadIdx.x;
    int tl0 = blockIdx.x * 32;
    int tm = tid >> 5, tn = tid & 31;
    float acc[4][4] = {};
    for (int kc = 0; kc < 32; kc++) {
        __syncthreads();
        #pragma unroll
        for (int r = 0; r < 4; r++) {            // stage A 32x32 (bf16 -> f32)
            int lin = r*256 + tid;
            int m = lin >> 5, kk = lin & 31;
            As[m][kk] = bf2f(o[(size_t)(tl0+m)*1024 + kc*32 + kk]);
        }
        #pragma unroll
        for (int r = 0; r < 4; r++) {            // stage B 32x128
            int lin = r*256 + tid;
            int kk = lin >> 5, nn = (lin & 31)*4;
            *(float4*)&Bs[kk][nn] = *(const float4*)(wo + (size_t)(kc*32+kk)*128 + nn);
        }
        __syncthreads();
        #pragma unroll
        for (int kk = 0; kk < 32; kk++) {
            float a0 = As[tm*4+0][kk];
            float a1 = As[tm*4+1][kk];
            float a2 = As[tm*4+2][kk];
            float a3 = As[tm*4+3][kk];
            float4 bv = *(const float4*)&Bs[kk][tn*4];
            acc[0][0] += a0*bv.x; acc[0][1] += a0*bv.y; acc[0][2] += a0*bv.z; acc[0][3] += a0*bv.w;
            acc[1][0] += a1*bv.x; acc[1][1] += a1*bv.y; acc[1][2] += a1*bv.z; acc[1][3] += a1*bv.w;
            acc[2][0] += a2*bv.x; acc[2][1] += a2*bv.y; acc[2][2] += a2*bv.z; acc[2][3] += a2*bv.w;
            acc[3][0] += a3*bv.x; acc[3][1] += a3*bv.y; acc[3][2] += a3*bv.z; acc[3][3] += a3*bv.w;
        }
    }
    #pragma unroll
    for (int ii = 0; ii < 4; ii++) {
        size_t hb = (size_t)(tokbase + tl0 + tm*4 + ii)*128;
        #pragma unroll
        for (int jj = 0; jj < 4; jj++) {
            int n = tn*4 + jj;
            h[hb + n] += acc[ii][jj] + bo[n];
        }
    }
}

// ---------------------------------------------------------------------------
// Kernel 6: head GEMM  h[B*W, 2048] @ w_head[2048,16] + b_head -> out
// grid = B*W, 256 threads
// ---------------------------------------------------------------------------
__global__ __launch_bounds__(256) void head_kernel(
    const float* __restrict__ h, const float* __restrict__ wh, const float* __restrict__ bh,
    float* __restrict__ out)
{
    int bw = blockIdx.x;
    int tid = threadIdx.x;
    __shared__ float hs[2048];
    __shared__ float red[16][17];
    #pragma unroll
    for (int r = 0; r < 8; r++) hs[r*256 + tid] = h[(size_t)bw*2048 + r*256 + tid];
    __syncthreads();
    int n = tid >> 4, l = tid & 15;
    float p = 0.f;
    #pragma unroll 8
    for (int m = 0; m < 128; m++) {
        int c = l + 16*m;
        p += hs[c]*wh[(size_t)c*16 + n];
    }
    red[n][l] = p;
    __syncthreads();
    if (l == 0) {
        float sacc = bh[n];
        #pragma unroll
        for (int jj = 0; jj < 16; jj++) sacc += red[n][jj];
        out[(size_t)bw*16 + n] = sacc;
    }
}

// ---------------------------------------------------------------------------
extern "C" void kernel_launch(void* const* d_in, const int* in_sizes, int n_in,
                              void* d_out, int out_size, void* d_ws, size_t ws_size,
                              hipStream_t stream)
{
    const float* x    = (const float*)d_in[0];
    const float* w1   = (const float*)d_in[1];
    const float* b1   = (const float*)d_in[2];
    const float* w2   = (const float*)d_in[3];
    const float* b2   = (const float*)d_in[4];
    const float* w3   = (const float*)d_in[5];
    const float* b3   = (const float*)d_in[6];
    const float* wval = (const float*)d_in[7];
    const float* bval = (const float*)d_in[8];
    const float* lng  = (const float*)d_in[9];
    const float* lnb  = (const float*)d_in[10];
    const float* wqkv = (const float*)d_in[11];
    const float* wout = (const float*)d_in[12];
    const float* bout = (const float*)d_in[13];
    const float* wh   = (const float*)d_in[14];
    const float* bh   = (const float*)d_in[15];
    float* out = (float*)d_out;

    char* ws = (char*)d_ws;
    float* h = (float*)ws;
    size_t off = (size_t)NTOK*128*4;               // 16.8 MB for h
    size_t fullbuf = (size_t)NTOK*1024*2;          // 67 MB per bf16 buffer
    size_t pbbuf   = (size_t)(WW*FF)*1024*2;       // 8.4 MB per-batch
    bool full = ws_size >= off + 4*fullbuf;
    size_t bsz = full ? fullbuf : pbbuf;
    bf16* q  = (bf16*)(ws + off);
    bf16* kk = (bf16*)(ws + off + bsz);
    bf16* vv = (bf16*)(ws + off + 2*bsz);
    bf16* oo = (bf16*)(ws + off + 3*bsz);
    int NBL = full ? 8 : 1;

    embed_kernel<<<BB*WW, 256, 0, stream>>>(x, w1,b1, w2,b2, w3,b3, wval, bval, h);

    for (int l = 0; l < 4; l++) {
        const float* wq_l = wqkv + (size_t)l*128*3072;
        const float* wo_l = wout + (size_t)l*1024*128;
        const float* g_l  = lng + l*128;
        const float* bl_l = lnb + l*128;
        const float* bo_l = bout + l*128;
        for (int bb = 0; bb < BB; bb += NBL) {
            int tokbase = bb*WW*FF;
            qkv_kernel<<<dim3(NBL*WW*FF/32, 24), 256, 0, stream>>>(
                h, wq_l, g_l, bl_l, q, kk, vv, tokbase);
            vattn_kernel<<<NBL*WW*HH, 256, 0, stream>>>(q, kk, vv, oo);
            tattn_kernel<<<NBL*FF*HH*16, 256, 0, stream>>>(q, kk, vv, oo);
            proj_kernel<<<NBL*WW*FF/32, 256, 0, stream>>>(oo, wo_l, bo_l, h, tokbase);
        }
    }

    head_kernel<<<BB*WW, 256, 0, stream>>>(h, wh, bh, out);
}

// Round 2
// 4363.328 us; speedup vs baseline: 2.2872x; 2.2872x over previous
//
#include <hip/hip_runtime.h>
#include <hip/hip_bf16.h>
#include <math.h>

#define BB 8
#define WW 256
#define FF 16
#define DD 128
#define HH 8
#define NTOK (BB*WW*FF)        // 32768
#define SCALE 0.08838834764831845f
#define INV_D (1.0f/128.0f)
#define LN10K_D 0.07195578415606394f   // ln(10000)/128

typedef __hip_bfloat16 bf16;
typedef short bf16x8 __attribute__((ext_vector_type(8)));   // 8 bf16 = 4 VGPRs
typedef float f32x4 __attribute__((ext_vector_type(4)));

__device__ __forceinline__ float bf2f(bf16 x){ return __bfloat162float(x); }
__device__ __forceinline__ bf16 f2bf(float x){ return __float2bfloat16(x); }
__device__ __forceinline__ unsigned short bfbits(float x){ bf16 b = f2bf(x); return *(unsigned short*)&b; }

#define MFMA16 __builtin_amdgcn_mfma_f32_16x16x32_bf16

// ---------------------------------------------------------------------------
// Kernel: causal convs + stack + @w_val + bias + sinusoidal PE -> h [B,W,F,D]
// ---------------------------------------------------------------------------
__global__ __launch_bounds__(256) void embed_kernel(
    const float* __restrict__ x,
    const float* __restrict__ w1, const float* __restrict__ b1,
    const float* __restrict__ w2, const float* __restrict__ b2,
    const float* __restrict__ w3, const float* __restrict__ b3,
    const float* __restrict__ wval, const float* __restrict__ bval,
    float* __restrict__ h)
{
    int bw = blockIdx.x;               // b*W + w
    int b = bw >> 8, w = bw & 255;
    int tid = threadIdx.x;
    __shared__ float s[FF][4];
    if (tid < 64) {
        int f = tid >> 2, t = tid & 3;
        const float* xb = x + (size_t)b*WW*FF + f;   // stride FF over time
        float v;
        if (t == 0) {
            v = xb[(size_t)w*FF];
        } else if (t == 1) {
            float acc = b1[f];
            #pragma unroll
            for (int kk = 0; kk < 4; kk++) { int t0 = w - (3-kk); if (t0 >= 0) acc += w1[f*4+kk]*xb[(size_t)t0*FF]; }
            v = acc;
        } else if (t == 2) {
            float acc = b2[f];
            #pragma unroll
            for (int kk = 0; kk < 8; kk++) { int t0 = w - (7-kk)*2; if (t0 >= 0) acc += w2[f*8+kk]*xb[(size_t)t0*FF]; }
            v = acc;
        } else {
            float acc = b3[f];
            #pragma unroll
            for (int kk = 0; kk < 16; kk++) { int t0 = w - (15-kk)*3; if (t0 >= 0) acc += w3[f*16+kk]*xb[(size_t)t0*FF]; }
            v = acc;
        }
        s[f][t] = v;
    }
    __syncthreads();
    #pragma unroll
    for (int r = 0; r < 8; r++) {
        int lin = r*256 + tid;
        int f = lin >> 7, d = lin & 127;
        float div = expf(-(float)(d & ~1) * LN10K_D);
        float arg = (float)w * div;
        float pe = (d & 1) ? cosf(arg) : sinf(arg);
        float e = bval[d] + pe;
        #pragma unroll
        for (int t = 0; t < 4; t++) e += s[f][t]*wval[t*128 + d];
        h[((size_t)bw*FF + f)*128 + d] = e;
    }
}

// ---------------------------------------------------------------------------
// Kernel: transpose+convert weights to bf16:  wqkvT[l][n(3072)][k(128)],
// woutT[l][n(128)][k(1024)].  Runs every launch (idempotent, graph-safe).
// ---------------------------------------------------------------------------
__global__ __launch_bounds__(256) void convert_w(
    const float* __restrict__ wqkv, const float* __restrict__ wout,
    bf16* __restrict__ wqkvT, bf16* __restrict__ woutT)
{
    int idx = blockIdx.x*256 + threadIdx.x;
    const int T1 = 4*3072*128;
    const int T2 = 4*128*1024;
    if (idx < T1) {
        int l = idx / (3072*128);
        int rem = idx % (3072*128);
        int n = rem / 128, kk2 = rem % 128;
        wqkvT[idx] = f2bf(wqkv[((size_t)l*128 + kk2)*3072 + n]);
    } else if (idx < T1 + T2) {
        int j = idx - T1;
        int l = j / (128*1024);
        int rem = j % (128*1024);
        int n = rem / 1024, kk2 = rem % 1024;
        woutT[j] = f2bf(wout[((size_t)l*1024 + kk2)*128 + n]);
    }
}

// ---------------------------------------------------------------------------
// Kernel: LayerNorm h(fp32) -> hn(bf16).  16 lanes per token, 8 elems each.
// grid = NTOK/16
// ---------------------------------------------------------------------------
__global__ __launch_bounds__(256) void ln_kernel(
    const float* __restrict__ h, const float* __restrict__ g,
    const float* __restrict__ b, bf16* __restrict__ hn)
{
    int tid = threadIdx.x;
    int tok = blockIdx.x*16 + (tid>>4);
    int sub = tid & 15;
    const float* hr = h + (size_t)tok*128 + sub*8;
    float xv[8];
    *(float4*)&xv[0] = *(const float4*)hr;
    *(float4*)&xv[4] = *(const float4*)(hr+4);
    float s1 = 0.f, s2 = 0.f;
    #pragma unroll
    for (int e = 0; e < 8; e++) { s1 += xv[e]; s2 += xv[e]*xv[e]; }
    #pragma unroll
    for (int m = 1; m < 16; m <<= 1) {
        s1 += __shfl_xor(s1, m, 64);
        s2 += __shfl_xor(s2, m, 64);
    }
    float mean = s1*INV_D;
    float var  = s2*INV_D - mean*mean;
    float rs = rsqrtf(var + 1e-5f);
    union { uint4 u; unsigned short sh[8]; } o;
    #pragma unroll
    for (int e = 0; e < 8; e++) {
        int d = sub*8 + e;
        o.sh[e] = bfbits((xv[e]-mean)*rs*g[d] + b[d]);
    }
    *(uint4*)(hn + (size_t)tok*128 + sub*8) = o.u;
}

// ---------------------------------------------------------------------------
// Kernel: QKV GEMM, MFMA, LDS-free.  A = hn [M x 128] bf16 (K-contig rows),
// B = wqkvT [3072 x 128] bf16 (K-contig rows).  Direct global frag loads:
// 4 quads x 16B cover one 64B sector per row -> perfectly coalesced.
// block 256 = 4 waves (2x2), wave tile 64x64, block tile 128x128.
// ---------------------------------------------------------------------------
__global__ __launch_bounds__(256) void qkv_mfma(
    const bf16* __restrict__ hn, const bf16* __restrict__ wT,
    bf16* __restrict__ q, bf16* __restrict__ k, bf16* __restrict__ v,
    int tokbase)
{
    int tid = threadIdx.x;
    int lane = tid & 63, wave = tid >> 6;
    int quad = lane >> 4, l16 = lane & 15;
    int wm = wave >> 1, wn = wave & 1;
    int m0 = blockIdx.x * 128, n0 = blockIdx.y * 128;

    f32x4 acc[4][4];
    #pragma unroll
    for (int a = 0; a < 4; a++)
        #pragma unroll
        for (int c = 0; c < 4; c++) acc[a][c] = 0.f;

    #pragma unroll
    for (int kt = 0; kt < 4; kt++) {
        int ko = kt*32 + quad*8;
        bf16x8 af[4], bfr[4];
        #pragma unroll
        for (int tm = 0; tm < 4; tm++)
            af[tm] = *(const bf16x8*)(hn + (size_t)(tokbase + m0 + wm*64 + tm*16 + l16)*128 + ko);
        #pragma unroll
        for (int tn = 0; tn < 4; tn++)
            bfr[tn] = *(const bf16x8*)(wT + (size_t)(n0 + wn*64 + tn*16 + l16)*128 + ko);
        #pragma unroll
        for (int tm = 0; tm < 4; tm++)
            #pragma unroll
            for (int tn = 0; tn < 4; tn++)
                acc[tm][tn] = MFMA16(af[tm], bfr[tn], acc[tm][tn], 0, 0, 0);
    }

    bf16* dst; int nrel; float scl;
    if (n0 < 1024)      { dst = q; nrel = n0;        scl = SCALE; }
    else if (n0 < 2048) { dst = k; nrel = n0 - 1024; scl = 1.0f; }
    else                { dst = v; nrel = n0 - 2048; scl = 1.0f; }
    #pragma unroll
    for (int tm = 0; tm < 4; tm++)
        #pragma unroll
        for (int tn = 0; tn < 4; tn++) {
            int gcol = nrel + wn*64 + tn*16 + l16;
            #pragma unroll
            for (int r = 0; r < 4; r++) {
                int grow = m0 + wm*64 + tm*16 + quad*4 + r;   // C-layout: row=quad*4+r, col=l16
                dst[(size_t)grow*1024 + gcol] = f2bf(acc[tm][tn][r]*scl);
            }
        }
}

// ---------------------------------------------------------------------------
// Kernel: variable attention (scalar; attend over F=16 per (b,w,h)). Writes o.
// ---------------------------------------------------------------------------
__global__ __launch_bounds__(256) void vattn_kernel(
    const bf16* __restrict__ q, const bf16* __restrict__ k, const bf16* __restrict__ v,
    bf16* __restrict__ o)
{
    int bx = blockIdx.x;
    int hh = bx & 7; int bw = bx >> 3;       // local b*W + w
    int tid = threadIdx.x;
    __shared__ float qs[16][129];
    __shared__ float ks[16][129];
    __shared__ float vs[16][129];
    __shared__ float S[16][17];
    __shared__ float rsum[16];
    #pragma unroll
    for (int r = 0; r < 8; r++) {
        int lin = r*256 + tid;
        int f = lin >> 7, d = lin & 127;
        size_t idx = ((size_t)bw*FF + f)*1024 + hh*128 + d;
        qs[f][d] = bf2f(q[idx]);
        ks[f][d] = bf2f(k[idx]);
        vs[f][d] = bf2f(v[idx]);
    }
    __syncthreads();
    int i = tid >> 4, j = tid & 15;
    float s = 0.f;
    #pragma unroll 16
    for (int d = 0; d < 128; d++) s += qs[i][d]*ks[j][d];
    S[i][j] = s;
    __syncthreads();
    float m = -INFINITY;
    #pragma unroll
    for (int jj = 0; jj < 16; jj++) m = fmaxf(m, S[i][jj]);
    float p = __expf(s - m);
    __syncthreads();
    S[i][j] = p;
    __syncthreads();
    if (j == 0) {
        float sm = 0.f;
        #pragma unroll
        for (int jj = 0; jj < 16; jj++) sm += S[i][jj];
        rsum[i] = sm;
    }
    __syncthreads();
    float inv = 1.f / rsum[i];
    float acc[8] = {};
    int dbase = j;
    #pragma unroll
    for (int jj = 0; jj < 16; jj++) {
        float pj = S[i][jj];
        #pragma unroll
        for (int r = 0; r < 8; r++) acc[r] += pj * vs[jj][dbase + 16*r];
    }
    size_t ob = ((size_t)bw*FF + i)*1024 + hh*128;
    #pragma unroll
    for (int r = 0; r < 8; r++) o[ob + dbase + 16*r] = f2bf(acc[r]*inv);
}

// ---------------------------------------------------------------------------
// Kernel: temporal attention, MFMA.  One block per (bl,f,h, 64-row i-tile).
// 4 waves; wave owns 16 Q-rows.  S (16x256) in regs, softmax via shfl_xor,
// P via LDS (C-layout -> A-layout round trip), V transposed into LDS with a
// rotation swizzle (<=2-way bank aliasing on both store and b128 read).
// o += P@V / l  (accumulates onto vattn output).
// ---------------------------------------------------------------------------
__global__ __launch_bounds__(256) void tattn_mfma(
    const bf16* __restrict__ q, const bf16* __restrict__ k, const bf16* __restrict__ v,
    bf16* __restrict__ o)
{
    __shared__ __align__(16) unsigned short VsT[128*72];      // [d][j+pad], swizzled
    __shared__ __align__(16) unsigned short Ps[4][16][264];   // per-wave P, 16x256 (+8 pad)

    int bx = blockIdx.x;
    int it = bx & 3, hh = (bx>>2)&7, f = (bx>>5)&15, bl = bx>>9;
    int i0 = it*64;
    int tid = threadIdx.x;
    int lane = tid & 63, wave = tid >> 6;
    int quad = lane >> 4, l16 = lane & 15;

    // base elem offset for (bl, f, hh); token j -> + j*16384
    size_t base = ((size_t)(bl*WW)*FF + f)*1024 + (size_t)hh*128;

    // --- Q fragments: direct global (A-layout: m=l16, k=quad*8+j) ---
    bf16x8 af[4];
    {
        size_t qa = base + (size_t)(i0 + wave*16 + l16)*16384;
        #pragma unroll
        for (int kt = 0; kt < 4; kt++)
            af[kt] = *(const bf16x8*)(q + qa + kt*32 + quad*8);
    }

    // --- phase 1: S = Q K^T, all 256 j in regs (16 N-tiles) ---
    f32x4 s_acc[16];
    #pragma unroll
    for (int t = 0; t < 16; t++) s_acc[t] = 0.f;
    #pragma unroll 4
    for (int t = 0; t < 16; t++) {
        size_t ja = base + (size_t)(t*16 + l16)*16384;
        #pragma unroll
        for (int kt = 0; kt < 4; kt++) {
            bf16x8 kf = *(const bf16x8*)(k + ja + kt*32 + quad*8);
            s_acc[t] = MFMA16(af[kt], kf, s_acc[t], 0, 0, 0);
        }
    }

    // --- phase 2: softmax over j (rows owned: quad*4+r; cols: t*16+l16) ---
    float mx[4], sm[4], inv[4];
    #pragma unroll
    for (int r = 0; r < 4; r++) mx[r] = -1e30f;
    #pragma unroll
    for (int t = 0; t < 16; t++)
        #pragma unroll
        for (int r = 0; r < 4; r++) mx[r] = fmaxf(mx[r], s_acc[t][r]);
    #pragma unroll
    for (int m = 1; m < 16; m <<= 1)
        #pragma unroll
        for (int r = 0; r < 4; r++) mx[r] = fmaxf(mx[r], __shfl_xor(mx[r], m, 64));
    #pragma unroll
    for (int r = 0; r < 4; r++) sm[r] = 0.f;
    #pragma unroll
    for (int t = 0; t < 16; t++)
        #pragma unroll
        for (int r = 0; r < 4; r++) {
            float p = __expf(s_acc[t][r] - mx[r]);
            s_acc[t][r] = p;
            sm[r] += p;
        }
    #pragma unroll
    for (int m = 1; m < 16; m <<= 1)
        #pragma unroll
        for (int r = 0; r < 4; r++) sm[r] += __shfl_xor(sm[r], m, 64);
    #pragma unroll
    for (int r = 0; r < 4; r++) inv[r] = 1.f / sm[r];

    // write P (bf16) to per-wave LDS in row-major [i][j]
    #pragma unroll
    for (int t = 0; t < 16; t++)
        #pragma unroll
        for (int r = 0; r < 4; r++)
            Ps[wave][quad*4+r][t*16+l16] = bfbits(s_acc[t][r]);

    // --- phase 3: O = P @ V over 4 j-tiles of 64, V^T staged in LDS ---
    f32x4 oacc[8];
    #pragma unroll
    for (int t = 0; t < 8; t++) oacc[t] = 0.f;

    int rr = tid >> 4, cc = (tid & 15)*8;
    for (int jt = 0; jt < 4; jt++) {
        // stage V^T: VsT[d][ (j + 8*(d>>3)) & 63 ] = V[j][d]
        #pragma unroll
        for (int r4 = 0; r4 < 4; r4++) {
            int j = r4*16 + rr;
            union { uint4 u; unsigned short sh[8]; } uu;
            uu.u = *(const uint4*)(v + base + (size_t)(jt*64 + j)*16384 + cc);
            int col = (j + ((tid & 7) << 3)) & 63;   // rot = 8*((d0+e)>>3 & 7) = 8*(tid&7)
            #pragma unroll
            for (int e = 0; e < 8; e++)
                VsT[(cc + e)*72 + col] = uu.sh[e];
        }
        __syncthreads();
        #pragma unroll
        for (int kt2 = 0; kt2 < 2; kt2++) {
            int kbase = kt2*32 + quad*8;
            bf16x8 pf = *(const bf16x8*)&Ps[wave][l16][jt*64 + kbase];
            #pragma unroll
            for (int t = 0; t < 8; t++) {
                int d = t*16 + l16;
                int colstart = (kbase + (((d>>3)&7) << 3)) & 63;
                bf16x8 vf = *(const bf16x8*)&VsT[d*72 + colstart];
                oacc[t] = MFMA16(pf, vf, oacc[t], 0, 0, 0);
            }
        }
        __syncthreads();   // protect VsT overwrite next iter
    }

    // --- epilogue: o += O / l  (C-layout rows quad*4+r, cols t*16+l16) ---
    #pragma unroll
    for (int r = 0; r < 4; r++) {
        size_t ob = base + (size_t)(i0 + wave*16 + quad*4 + r)*16384;
        #pragma unroll
        for (int t = 0; t < 8; t++) {
            size_t idx = ob + t*16 + l16;
            o[idx] = f2bf(bf2f(o[idx]) + oacc[t][r]*inv[r]);
        }
    }
}

// ---------------------------------------------------------------------------
// Kernel: out-projection, MFMA, LDS-free.  A = o [M x 1024] bf16,
// B = woutT [128 x 1024] bf16 (both K-contig rows, direct frag loads).
// h += A@B + bias (residual).
// ---------------------------------------------------------------------------
__global__ __launch_bounds__(256) void proj_mfma(
    const bf16* __restrict__ o, const bf16* __restrict__ woT,
    const float* __restrict__ bo, float* __restrict__ h, int tokbase)
{
    int tid = threadIdx.x;
    int lane = tid & 63, wave = tid >> 6;
    int quad = lane >> 4, l16 = lane & 15;
    int wm = wave >> 1, wn = wave & 1;
    int m0 = blockIdx.x * 128;

    f32x4 acc[4][4];
    #pragma unroll
    for (int a = 0; a < 4; a++)
        #pragma unroll
        for (int c = 0; c < 4; c++) acc[a][c] = 0.f;

    for (int kc = 0; kc < 32; kc++) {
        int ko = kc*32 + quad*8;
        bf16x8 af[4], bfr[4];
        #pragma unroll
        for (int tm = 0; tm < 4; tm++)
            af[tm] = *(const bf16x8*)(o + (size_t)(m0 + wm*64 + tm*16 + l16)*1024 + ko);
        #pragma unroll
        for (int tn = 0; tn < 4; tn++)
            bfr[tn] = *(const bf16x8*)(woT + (size_t)(wn*64 + tn*16 + l16)*1024 + ko);
        #pragma unroll
        for (int tm = 0; tm < 4; tm++)
            #pragma unroll
            for (int tn = 0; tn < 4; tn++)
                acc[tm][tn] = MFMA16(af[tm], bfr[tn], acc[tm][tn], 0, 0, 0);
    }

    #pragma unroll
    for (int tm = 0; tm < 4; tm++)
        #pragma unroll
        for (int tn = 0; tn < 4; tn++) {
            int gcol = wn*64 + tn*16 + l16;
            #pragma unroll
            for (int r = 0; r < 4; r++) {
                int grow = m0 + wm*64 + tm*16 + quad*4 + r;
                size_t idx = (size_t)(tokbase + grow)*128 + gcol;
                h[idx] += acc[tm][tn][r] + bo[gcol];
            }
        }
}

// ---------------------------------------------------------------------------
// Kernel: head GEMM  h[B*W, 2048] @ w_head[2048,16] + b_head -> out
// ---------------------------------------------------------------------------
__global__ __launch_bounds__(256) void head_kernel(
    const float* __restrict__ h, const float* __restrict__ wh, const float* __restrict__ bh,
    float* __restrict__ out)
{
    int bw = blockIdx.x;
    int tid = threadIdx.x;
    __shared__ float hs[2048];
    __shared__ float red[16][17];
    #pragma unroll
    for (int r = 0; r < 8; r++) hs[r*256 + tid] = h[(size_t)bw*2048 + r*256 + tid];
    __syncthreads();
    int n = tid >> 4, l = tid & 15;
    float p = 0.f;
    #pragma unroll 8
    for (int m = 0; m < 128; m++) {
        int c = l + 16*m;
        p += hs[c]*wh[(size_t)c*16 + n];
    }
    red[n][l] = p;
    __syncthreads();
    if (l == 0) {
        float sacc = bh[n];
        #pragma unroll
        for (int jj = 0; jj < 16; jj++) sacc += red[n][jj];
        out[(size_t)bw*16 + n] = sacc;
    }
}

// ---------------------------------------------------------------------------
extern "C" void kernel_launch(void* const* d_in, const int* in_sizes, int n_in,
                              void* d_out, int out_size, void* d_ws, size_t ws_size,
                              hipStream_t stream)
{
    const float* x    = (const float*)d_in[0];
    const float* w1   = (const float*)d_in[1];
    const float* b1   = (const float*)d_in[2];
    const float* w2   = (const float*)d_in[3];
    const float* b2   = (const float*)d_in[4];
    const float* w3   = (const float*)d_in[5];
    const float* b3   = (const float*)d_in[6];
    const float* wval = (const float*)d_in[7];
    const float* bval = (const float*)d_in[8];
    const float* lng  = (const float*)d_in[9];
    const float* lnb  = (const float*)d_in[10];
    const float* wqkv = (const float*)d_in[11];
    const float* wout = (const float*)d_in[12];
    const float* bout = (const float*)d_in[13];
    const float* wh   = (const float*)d_in[14];
    const float* bh   = (const float*)d_in[15];
    float* out = (float*)d_out;

    char* ws = (char*)d_ws;
    bf16*  wqkvT = (bf16*)ws;                      // 3,145,728 B
    bf16*  woutT = (bf16*)(ws + 3145728);          // 1,048,576 B
    float* h     = (float*)(ws + 4194304);         // 16,777,216 B
    bf16*  hn    = (bf16*)(ws + 20971520);         //  8,388,608 B
    size_t qoff  = 29360128;
    size_t fullb = 67108864ull, pbb = 8388608ull;
    bool full = ws_size >= qoff + 4*fullb;         // 297,795,584 B
    size_t bsz = full ? fullb : pbb;
    bf16* q  = (bf16*)(ws + qoff);
    bf16* kk = (bf16*)(ws + qoff + bsz);
    bf16* vv = (bf16*)(ws + qoff + 2*bsz);
    bf16* oo = (bf16*)(ws + qoff + 3*bsz);
    int NBL = full ? 8 : 1;

    convert_w<<<8192, 256, 0, stream>>>(wqkv, wout, wqkvT, woutT);
    embed_kernel<<<BB*WW, 256, 0, stream>>>(x, w1,b1, w2,b2, w3,b3, wval, bval, h);

    for (int l = 0; l < 4; l++) {
        const bf16* wqT_l = wqkvT + (size_t)l*3072*128;
        const bf16* woT_l = woutT + (size_t)l*128*1024;
        const float* bo_l = bout + l*128;
        ln_kernel<<<NTOK/16, 256, 0, stream>>>(h, lng + l*128, lnb + l*128, hn);
        for (int bb = 0; bb < BB; bb += NBL) {
            int tokbase = bb*WW*FF;
            qkv_mfma<<<dim3(NBL*WW*FF/128, 24), 256, 0, stream>>>(
                hn, wqT_l, q, kk, vv, tokbase);
            vattn_kernel<<<NBL*WW*HH, 256, 0, stream>>>(q, kk, vv, oo);
            tattn_mfma<<<NBL*FF*HH*4, 256, 0, stream>>>(q, kk, vv, oo);
            proj_mfma<<<NBL*WW*FF/128, 256, 0, stream>>>(oo, woT_l, bo_l, h, tokbase);
        }
    }

    head_kernel<<<BB*WW, 256, 0, stream>>>(h, wh, bh, out);
}

// Round 3
// 2846.295 us; speedup vs baseline: 3.5062x; 1.5330x over previous
//
#include <hip/hip_runtime.h>
#include <hip/hip_bf16.h>
#include <math.h>

#define BB 8
#define WW 256
#define FF 16
#define DD 128
#define HH 8
#define NTOK (BB*WW*FF)        // 32768
#define SCALE 0.08838834764831845f
#define INV_D (1.0f/128.0f)
#define LN10K_D 0.07195578415606394f   // ln(10000)/128

typedef __hip_bfloat16 bf16;
typedef short bf16x8 __attribute__((ext_vector_type(8)));   // 8 bf16 = 4 VGPRs
typedef float f32x4 __attribute__((ext_vector_type(4)));

__device__ __forceinline__ float bf2f(bf16 x){ return __bfloat162float(x); }
__device__ __forceinline__ bf16 f2bf(float x){ return __float2bfloat16(x); }
__device__ __forceinline__ unsigned short bfbits(float x){ bf16 b = f2bf(x); return *(unsigned short*)&b; }

#define MFMA16 __builtin_amdgcn_mfma_f32_16x16x32_bf16

// ---------------------------------------------------------------------------
// causal convs + stack + @w_val + bias + sinusoidal PE -> h [B,W,F,D]
// ---------------------------------------------------------------------------
__global__ __launch_bounds__(256) void embed_kernel(
    const float* __restrict__ x,
    const float* __restrict__ w1, const float* __restrict__ b1,
    const float* __restrict__ w2, const float* __restrict__ b2,
    const float* __restrict__ w3, const float* __restrict__ b3,
    const float* __restrict__ wval, const float* __restrict__ bval,
    float* __restrict__ h)
{
    int bw = blockIdx.x;               // b*W + w
    int b = bw >> 8, w = bw & 255;
    int tid = threadIdx.x;
    __shared__ float s[FF][4];
    if (tid < 64) {
        int f = tid >> 2, t = tid & 3;
        const float* xb = x + (size_t)b*WW*FF + f;   // stride FF over time
        float v;
        if (t == 0) {
            v = xb[(size_t)w*FF];
        } else if (t == 1) {
            float acc = b1[f];
            #pragma unroll
            for (int kk = 0; kk < 4; kk++) { int t0 = w - (3-kk); if (t0 >= 0) acc += w1[f*4+kk]*xb[(size_t)t0*FF]; }
            v = acc;
        } else if (t == 2) {
            float acc = b2[f];
            #pragma unroll
            for (int kk = 0; kk < 8; kk++) { int t0 = w - (7-kk)*2; if (t0 >= 0) acc += w2[f*8+kk]*xb[(size_t)t0*FF]; }
            v = acc;
        } else {
            float acc = b3[f];
            #pragma unroll
            for (int kk = 0; kk < 16; kk++) { int t0 = w - (15-kk)*3; if (t0 >= 0) acc += w3[f*16+kk]*xb[(size_t)t0*FF]; }
            v = acc;
        }
        s[f][t] = v;
    }
    __syncthreads();
    #pragma unroll
    for (int r = 0; r < 8; r++) {
        int lin = r*256 + tid;
        int f = lin >> 7, d = lin & 127;
        float div = expf(-(float)(d & ~1) * LN10K_D);
        float arg = (float)w * div;
        float pe = (d & 1) ? cosf(arg) : sinf(arg);
        float e = bval[d] + pe;
        #pragma unroll
        for (int t = 0; t < 4; t++) e += s[f][t]*wval[t*128 + d];
        h[((size_t)bw*FF + f)*128 + d] = e;
    }
}

// ---------------------------------------------------------------------------
// transpose+convert weights to bf16: wqkvT[l][n(3072)][k(128)],
// woutT[l][n(128)][k(1024)], whT[n(16)][k(2048)].
// ---------------------------------------------------------------------------
__global__ __launch_bounds__(256) void convert_w(
    const float* __restrict__ wqkv, const float* __restrict__ wout,
    const float* __restrict__ wh,
    bf16* __restrict__ wqkvT, bf16* __restrict__ woutT, bf16* __restrict__ whT)
{
    int idx = blockIdx.x*256 + threadIdx.x;
    const int T1 = 4*3072*128;     // 1,572,864
    const int T2 = 4*128*1024;     //   524,288
    const int T3 = 16*2048;        //    32,768
    if (idx < T1) {
        int l = idx / (3072*128);
        int rem = idx % (3072*128);
        int n = rem / 128, kk2 = rem % 128;
        wqkvT[idx] = f2bf(wqkv[((size_t)l*128 + kk2)*3072 + n]);
    } else if (idx < T1 + T2) {
        int j = idx - T1;
        int l = j / (128*1024);
        int rem = j % (128*1024);
        int n = rem / 1024, kk2 = rem % 1024;
        woutT[j] = f2bf(wout[((size_t)l*1024 + kk2)*128 + n]);
    } else if (idx < T1 + T2 + T3) {
        int j = idx - T1 - T2;
        int n = j >> 11, kk2 = j & 2047;
        whT[j] = f2bf(wh[(size_t)kk2*16 + n]);
    }
}

// ---------------------------------------------------------------------------
// LayerNorm h(fp32) -> hn(bf16).  16 lanes per token.
// ---------------------------------------------------------------------------
__global__ __launch_bounds__(256) void ln_kernel(
    const float* __restrict__ h, const float* __restrict__ g,
    const float* __restrict__ b, bf16* __restrict__ hn)
{
    int tid = threadIdx.x;
    int tok = blockIdx.x*16 + (tid>>4);
    int sub = tid & 15;
    const float* hr = h + (size_t)tok*128 + sub*8;
    float xv[8];
    *(float4*)&xv[0] = *(const float4*)hr;
    *(float4*)&xv[4] = *(const float4*)(hr+4);
    float s1 = 0.f, s2 = 0.f;
    #pragma unroll
    for (int e = 0; e < 8; e++) { s1 += xv[e]; s2 += xv[e]*xv[e]; }
    #pragma unroll
    for (int m = 1; m < 16; m <<= 1) {
        s1 += __shfl_xor(s1, m, 64);
        s2 += __shfl_xor(s2, m, 64);
    }
    float mean = s1*INV_D;
    float var  = s2*INV_D - mean*mean;
    float rs = rsqrtf(var + 1e-5f);
    union { uint4 u; unsigned short sh[8]; } o;
    #pragma unroll
    for (int e = 0; e < 8; e++) {
        int d = sub*8 + e;
        o.sh[e] = bfbits((xv[e]-mean)*rs*g[d] + b[d]);
    }
    *(uint4*)(hn + (size_t)tok*128 + sub*8) = o.u;
}

// ---------------------------------------------------------------------------
// QKV GEMM, MFMA, LDS-free (direct global frag loads, K-contig rows both sides)
// ---------------------------------------------------------------------------
__global__ __launch_bounds__(256) void qkv_mfma(
    const bf16* __restrict__ hn, const bf16* __restrict__ wT,
    bf16* __restrict__ q, bf16* __restrict__ k, bf16* __restrict__ v,
    int tokbase)
{
    int tid = threadIdx.x;
    int lane = tid & 63, wave = tid >> 6;
    int quad = lane >> 4, l16 = lane & 15;
    int wm = wave >> 1, wn = wave & 1;
    int m0 = blockIdx.x * 128, n0 = blockIdx.y * 128;

    f32x4 acc[4][4];
    #pragma unroll
    for (int a = 0; a < 4; a++)
        #pragma unroll
        for (int c = 0; c < 4; c++) acc[a][c] = 0.f;

    #pragma unroll
    for (int kt = 0; kt < 4; kt++) {
        int ko = kt*32 + quad*8;
        bf16x8 af[4], bfr[4];
        #pragma unroll
        for (int tm = 0; tm < 4; tm++)
            af[tm] = *(const bf16x8*)(hn + (size_t)(tokbase + m0 + wm*64 + tm*16 + l16)*128 + ko);
        #pragma unroll
        for (int tn = 0; tn < 4; tn++)
            bfr[tn] = *(const bf16x8*)(wT + (size_t)(n0 + wn*64 + tn*16 + l16)*128 + ko);
        #pragma unroll
        for (int tm = 0; tm < 4; tm++)
            #pragma unroll
            for (int tn = 0; tn < 4; tn++)
                acc[tm][tn] = MFMA16(af[tm], bfr[tn], acc[tm][tn], 0, 0, 0);
    }

    bf16* dst; int nrel; float scl;
    if (n0 < 1024)      { dst = q; nrel = n0;        scl = SCALE; }
    else if (n0 < 2048) { dst = k; nrel = n0 - 1024; scl = 1.0f; }
    else                { dst = v; nrel = n0 - 2048; scl = 1.0f; }
    #pragma unroll
    for (int tm = 0; tm < 4; tm++)
        #pragma unroll
        for (int tn = 0; tn < 4; tn++) {
            int gcol = nrel + wn*64 + tn*16 + l16;
            #pragma unroll
            for (int r = 0; r < 4; r++) {
                int grow = m0 + wm*64 + tm*16 + quad*4 + r;   // C: row=quad*4+r, col=l16
                dst[(size_t)grow*1024 + gcol] = f2bf(acc[tm][tn][r]*scl);
            }
        }
}

// ---------------------------------------------------------------------------
// variable attention, MFMA.  One block per (bl,w); 4 waves x 2 heads each.
// V^T block-staged in LDS (rows padded to 24 elems: 48B = 16B-aligned, b128
// reads 2-way aliased = free; staging stores are 64-way conflicted but cost
// ~0.6us/block total).  S via QK^T MFMA, softmax in regs (shfl over l16),
// P transposed through per-wave LDS, O = P(zero-padded K=32) @ V.  Writes o.
// ---------------------------------------------------------------------------
__global__ __launch_bounds__(256) void vattn_mfma(
    const bf16* __restrict__ q, const bf16* __restrict__ k, const bf16* __restrict__ v,
    bf16* __restrict__ o)
{
    __shared__ __align__(16) unsigned short VsT[1024*24];   // 49,152 B
    __shared__ __align__(16) unsigned short Ps[4][16][24];  //  3,072 B
    int tid = threadIdx.x;
    int lane = tid & 63, wave = tid >> 6, quad = lane >> 4, l16 = lane & 15;
    size_t base = (size_t)blockIdx.x * 16384;   // (bl*256+w)*16 tokens * 1024

    // stage V^T for all heads: VsT[d][j] = V[j][d]
    #pragma unroll
    for (int p = 0; p < 8; p++) {
        int lin = p*256 + tid;
        int j = lin >> 7, d0 = (lin & 127)*8;
        union { uint4 u; unsigned short sh[8]; } uu;
        uu.u = *(const uint4*)(v + base + (size_t)j*1024 + d0);
        #pragma unroll
        for (int e = 0; e < 8; e++) VsT[(d0+e)*24 + j] = uu.sh[e];
    }
    __syncthreads();

    bf16x8 zf = {0,0,0,0,0,0,0,0};
    #pragma unroll
    for (int hi = 0; hi < 2; hi++) {
        int hh = wave*2 + hi;
        size_t hb = base + hh*128;

        // S = Q K^T  (A: lane m=l16 = i(f); B: lane n=l16 = j(f); k=d)
        f32x4 s = {0.f,0.f,0.f,0.f};
        #pragma unroll
        for (int kt = 0; kt < 4; kt++) {
            bf16x8 qf = *(const bf16x8*)(q + hb + (size_t)l16*1024 + kt*32 + quad*8);
            bf16x8 kf = *(const bf16x8*)(k + hb + (size_t)l16*1024 + kt*32 + quad*8);
            s = MFMA16(qf, kf, s, 0, 0, 0);
        }
        // softmax over j (=l16 direction); rows i = quad*4+r
        float p[4];
        #pragma unroll
        for (int r = 0; r < 4; r++) {
            float mx = s[r];
            #pragma unroll
            for (int m = 1; m < 16; m <<= 1) mx = fmaxf(mx, __shfl_xor(mx, m, 64));
            float e = __expf(s[r] - mx);
            float sm = e;
            #pragma unroll
            for (int m = 1; m < 16; m <<= 1) sm += __shfl_xor(sm, m, 64);
            p[r] = e / sm;
        }
        __syncthreads();           // prior iteration's Ps reads complete
        #pragma unroll
        for (int r = 0; r < 4; r++) Ps[wave][quad*4+r][l16] = bfbits(p[r]);
        __syncthreads();

        // O = P @ V : A-frag from Ps (K=32, j>=16 zero), B-frag from VsT
        bf16x8 pf = zf;
        if (quad < 2) pf = *(const bf16x8*)&Ps[wave][l16][quad*8];
        f32x4 oa[8];
        #pragma unroll
        for (int dt = 0; dt < 8; dt++) oa[dt] = 0.f;
        #pragma unroll
        for (int dt = 0; dt < 8; dt++) {
            bf16x8 vf = zf;
            if (quad < 2) vf = *(const bf16x8*)&VsT[(size_t)(hh*128 + dt*16 + l16)*24 + quad*8];
            oa[dt] = MFMA16(pf, vf, oa[dt], 0, 0, 0);
        }
        #pragma unroll
        for (int r = 0; r < 4; r++) {
            size_t ob = base + (size_t)(quad*4+r)*1024 + hh*128;
            #pragma unroll
            for (int dt = 0; dt < 8; dt++)
                o[ob + dt*16 + l16] = f2bf(oa[dt][r]);
        }
    }
}

// ---------------------------------------------------------------------------
// temporal attention, MFMA.  Block per (bl,f,h, 64-row i-tile).  o += P@V/l.
// ---------------------------------------------------------------------------
__global__ __launch_bounds__(256) void tattn_mfma(
    const bf16* __restrict__ q, const bf16* __restrict__ k, const bf16* __restrict__ v,
    bf16* __restrict__ o)
{
    __shared__ __align__(16) unsigned short VsT[128*72];      // [d][j+pad], swizzled
    __shared__ __align__(16) unsigned short Ps[4][16][264];   // per-wave P, 16x256 (+8 pad)

    int bx = blockIdx.x;
    int it = bx & 3, hh = (bx>>2)&7, f = (bx>>5)&15, bl = bx>>9;
    int i0 = it*64;
    int tid = threadIdx.x;
    int lane = tid & 63, wave = tid >> 6;
    int quad = lane >> 4, l16 = lane & 15;

    size_t base = ((size_t)(bl*WW)*FF + f)*1024 + (size_t)hh*128;

    bf16x8 af[4];
    {
        size_t qa = base + (size_t)(i0 + wave*16 + l16)*16384;
        #pragma unroll
        for (int kt = 0; kt < 4; kt++)
            af[kt] = *(const bf16x8*)(q + qa + kt*32 + quad*8);
    }

    // phase 1: S = Q K^T, all 256 j in regs
    f32x4 s_acc[16];
    #pragma unroll
    for (int t = 0; t < 16; t++) s_acc[t] = 0.f;
    #pragma unroll 4
    for (int t = 0; t < 16; t++) {
        size_t ja = base + (size_t)(t*16 + l16)*16384;
        #pragma unroll
        for (int kt = 0; kt < 4; kt++) {
            bf16x8 kf = *(const bf16x8*)(k + ja + kt*32 + quad*8);
            s_acc[t] = MFMA16(af[kt], kf, s_acc[t], 0, 0, 0);
        }
    }

    // phase 2: softmax
    float mx[4], sm[4], inv[4];
    #pragma unroll
    for (int r = 0; r < 4; r++) mx[r] = -1e30f;
    #pragma unroll
    for (int t = 0; t < 16; t++)
        #pragma unroll
        for (int r = 0; r < 4; r++) mx[r] = fmaxf(mx[r], s_acc[t][r]);
    #pragma unroll
    for (int m = 1; m < 16; m <<= 1)
        #pragma unroll
        for (int r = 0; r < 4; r++) mx[r] = fmaxf(mx[r], __shfl_xor(mx[r], m, 64));
    #pragma unroll
    for (int r = 0; r < 4; r++) sm[r] = 0.f;
    #pragma unroll
    for (int t = 0; t < 16; t++)
        #pragma unroll
        for (int r = 0; r < 4; r++) {
            float p = __expf(s_acc[t][r] - mx[r]);
            s_acc[t][r] = p;
            sm[r] += p;
        }
    #pragma unroll
    for (int m = 1; m < 16; m <<= 1)
        #pragma unroll
        for (int r = 0; r < 4; r++) sm[r] += __shfl_xor(sm[r], m, 64);
    #pragma unroll
    for (int r = 0; r < 4; r++) inv[r] = 1.f / sm[r];

    #pragma unroll
    for (int t = 0; t < 16; t++)
        #pragma unroll
        for (int r = 0; r < 4; r++)
            Ps[wave][quad*4+r][t*16+l16] = bfbits(s_acc[t][r]);

    // phase 3: O = P @ V, V^T staged with rotation swizzle
    f32x4 oacc[8];
    #pragma unroll
    for (int t = 0; t < 8; t++) oacc[t] = 0.f;

    int rr = tid >> 4, cc = (tid & 15)*8;
    for (int jt = 0; jt < 4; jt++) {
        #pragma unroll
        for (int r4 = 0; r4 < 4; r4++) {
            int j = r4*16 + rr;
            union { uint4 u; unsigned short sh[8]; } uu;
            uu.u = *(const uint4*)(v + base + (size_t)(jt*64 + j)*16384 + cc);
            int col = (j + ((tid & 7) << 3)) & 63;
            #pragma unroll
            for (int e = 0; e < 8; e++)
                VsT[(cc + e)*72 + col] = uu.sh[e];
        }
        __syncthreads();
        #pragma unroll
        for (int kt2 = 0; kt2 < 2; kt2++) {
            int kbase = kt2*32 + quad*8;
            bf16x8 pf = *(const bf16x8*)&Ps[wave][l16][jt*64 + kbase];
            #pragma unroll
            for (int t = 0; t < 8; t++) {
                int d = t*16 + l16;
                int colstart = (kbase + (((d>>3)&7) << 3)) & 63;
                bf16x8 vf = *(const bf16x8*)&VsT[d*72 + colstart];
                oacc[t] = MFMA16(pf, vf, oacc[t], 0, 0, 0);
            }
        }
        __syncthreads();
    }

    #pragma unroll
    for (int r = 0; r < 4; r++) {
        size_t ob = base + (size_t)(i0 + wave*16 + quad*4 + r)*16384;
        #pragma unroll
        for (int t = 0; t < 8; t++) {
            size_t idx = ob + t*16 + l16;
            o[idx] = f2bf(bf2f(o[idx]) + oacc[t][r]*inv[r]);
        }
    }
}

// ---------------------------------------------------------------------------
// out-projection, MFMA, LDS-free.  h += o @ woutT^T + bias.
// ---------------------------------------------------------------------------
__global__ __launch_bounds__(256) void proj_mfma(
    const bf16* __restrict__ o, const bf16* __restrict__ woT,
    const float* __restrict__ bo, float* __restrict__ h, int tokbase)
{
    int tid = threadIdx.x;
    int lane = tid & 63, wave = tid >> 6;
    int quad = lane >> 4, l16 = lane & 15;
    int wm = wave >> 1, wn = wave & 1;
    int m0 = blockIdx.x * 128;

    f32x4 acc[4][4];
    #pragma unroll
    for (int a = 0; a < 4; a++)
        #pragma unroll
        for (int c = 0; c < 4; c++) acc[a][c] = 0.f;

    for (int kc = 0; kc < 32; kc++) {
        int ko = kc*32 + quad*8;
        bf16x8 af[4], bfr[4];
        #pragma unroll
        for (int tm = 0; tm < 4; tm++)
            af[tm] = *(const bf16x8*)(o + (size_t)(m0 + wm*64 + tm*16 + l16)*1024 + ko);
        #pragma unroll
        for (int tn = 0; tn < 4; tn++)
            bfr[tn] = *(const bf16x8*)(woT + (size_t)(wn*64 + tn*16 + l16)*1024 + ko);
        #pragma unroll
        for (int tm = 0; tm < 4; tm++)
            #pragma unroll
            for (int tn = 0; tn < 4; tn++)
                acc[tm][tn] = MFMA16(af[tm], bfr[tn], acc[tm][tn], 0, 0, 0);
    }

    #pragma unroll
    for (int tm = 0; tm < 4; tm++)
        #pragma unroll
        for (int tn = 0; tn < 4; tn++) {
            int gcol = wn*64 + tn*16 + l16;
            #pragma unroll
            for (int r = 0; r < 4; r++) {
                int grow = m0 + wm*64 + tm*16 + quad*4 + r;
                size_t idx = (size_t)(tokbase + grow)*128 + gcol;
                h[idx] += acc[tm][tn][r] + bo[gcol];
            }
        }
}

// ---------------------------------------------------------------------------
// head, MFMA: out[2048,16] = h[2048,2048]@whT^T + bh.  16 tokens/block,
// K=2048 split over 4 waves, LDS reduce.
// ---------------------------------------------------------------------------
__global__ __launch_bounds__(256) void head_mfma(
    const float* __restrict__ h, const bf16* __restrict__ whT,
    const float* __restrict__ bh, float* __restrict__ out)
{
    __shared__ float sred[4][16][17];
    int tid = threadIdx.x;
    int lane = tid & 63, wave = tid >> 6, quad = lane >> 4, l16 = lane & 15;
    int bw0 = blockIdx.x * 16;
    const float* hrow = h + (size_t)(bw0 + l16)*2048 + wave*512;
    const bf16* wrow  = whT + (size_t)l16*2048 + wave*512;

    f32x4 acc = {0.f,0.f,0.f,0.f};
    #pragma unroll 4
    for (int kc = 0; kc < 16; kc++) {
        int ko = kc*32 + quad*8;
        float4 a0 = *(const float4*)(hrow + ko);
        float4 a1 = *(const float4*)(hrow + ko + 4);
        union { bf16x8 v; unsigned short sh[8]; } ua;
        ua.sh[0]=bfbits(a0.x); ua.sh[1]=bfbits(a0.y); ua.sh[2]=bfbits(a0.z); ua.sh[3]=bfbits(a0.w);
        ua.sh[4]=bfbits(a1.x); ua.sh[5]=bfbits(a1.y); ua.sh[6]=bfbits(a1.z); ua.sh[7]=bfbits(a1.w);
        bf16x8 bv = *(const bf16x8*)(wrow + ko);
        acc = MFMA16(ua.v, bv, acc, 0, 0, 0);
    }
    #pragma unroll
    for (int r = 0; r < 4; r++) sred[wave][quad*4+r][l16] = acc[r];
    __syncthreads();
    int i = tid >> 4, n = tid & 15;
    float s = bh[n] + sred[0][i][n] + sred[1][i][n] + sred[2][i][n] + sred[3][i][n];
    out[(size_t)(bw0 + i)*16 + n] = s;
}

// ---------------------------------------------------------------------------
extern "C" void kernel_launch(void* const* d_in, const int* in_sizes, int n_in,
                              void* d_out, int out_size, void* d_ws, size_t ws_size,
                              hipStream_t stream)
{
    const float* x    = (const float*)d_in[0];
    const float* w1   = (const float*)d_in[1];
    const float* b1   = (const float*)d_in[2];
    const float* w2   = (const float*)d_in[3];
    const float* b2   = (const float*)d_in[4];
    const float* w3   = (const float*)d_in[5];
    const float* b3   = (const float*)d_in[6];
    const float* wval = (const float*)d_in[7];
    const float* bval = (const float*)d_in[8];
    const float* lng  = (const float*)d_in[9];
    const float* lnb  = (const float*)d_in[10];
    const float* wqkv = (const float*)d_in[11];
    const float* wout = (const float*)d_in[12];
    const float* bout = (const float*)d_in[13];
    const float* wh   = (const float*)d_in[14];
    const float* bh   = (const float*)d_in[15];
    float* out = (float*)d_out;

    char* ws = (char*)d_ws;
    bf16*  wqkvT = (bf16*)ws;                       // 3,145,728 B
    bf16*  woutT = (bf16*)(ws + 3145728);           // 1,048,576 B
    bf16*  whT   = (bf16*)(ws + 4194304);           //    65,536 B
    float* h     = (float*)(ws + 4259840);          // 16,777,216 B
    bf16*  hn    = (bf16*)(ws + 21037056);          //  8,388,608 B
    const size_t qoff = 29425664ull;

    // adaptive batch-chunking: largest NBL whose q/k/v/o buffers fit d_ws
    int NBL = 1;
    if      (ws_size >= qoff + 8ull*4ull*8388608ull) NBL = 8;
    else if (ws_size >= qoff + 4ull*4ull*8388608ull) NBL = 4;
    else if (ws_size >= qoff + 2ull*4ull*8388608ull) NBL = 2;
    size_t bsz = (size_t)NBL * 8388608ull;
    bf16* q  = (bf16*)(ws + qoff);
    bf16* kk = (bf16*)(ws + qoff + bsz);
    bf16* vv = (bf16*)(ws + qoff + 2*bsz);
    bf16* oo = (bf16*)(ws + qoff + 3*bsz);

    convert_w<<<8320, 256, 0, stream>>>(wqkv, wout, wh, wqkvT, woutT, whT);
    embed_kernel<<<BB*WW, 256, 0, stream>>>(x, w1,b1, w2,b2, w3,b3, wval, bval, h);

    for (int l = 0; l < 4; l++) {
        const bf16* wqT_l = wqkvT + (size_t)l*3072*128;
        const bf16* woT_l = woutT + (size_t)l*128*1024;
        const float* bo_l = bout + l*128;
        ln_kernel<<<NTOK/16, 256, 0, stream>>>(h, lng + l*128, lnb + l*128, hn);
        for (int bb = 0; bb < BB; bb += NBL) {
            int tokbase = bb*WW*FF;
            qkv_mfma<<<dim3(NBL*32, 24), 256, 0, stream>>>(
                hn, wqT_l, q, kk, vv, tokbase);
            vattn_mfma<<<NBL*WW, 256, 0, stream>>>(q, kk, vv, oo);
            tattn_mfma<<<NBL*FF*HH*4, 256, 0, stream>>>(q, kk, vv, oo);
            proj_mfma<<<NBL*32, 256, 0, stream>>>(oo, woT_l, bo_l, h, tokbase);
        }
    }

    head_mfma<<<BB*WW/16, 256, 0, stream>>>(h, whT, bh, out);
}

// Round 4
// 2622.789 us; speedup vs baseline: 3.8050x; 1.0852x over previous
//
#include <hip/hip_runtime.h>
#include <hip/hip_bf16.h>
#include <math.h>

#define BB 8
#define WW 256
#define FF 16
#define DD 128
#define HH 8
#define NTOK (BB*WW*FF)        // 32768
#define SCALE 0.08838834764831845f
#define INV_D (1.0f/128.0f)
#define LN10K_D 0.07195578415606394f   // ln(10000)/128

typedef __hip_bfloat16 bf16;
typedef short bf16x8 __attribute__((ext_vector_type(8)));   // 8 bf16 = 4 VGPRs
typedef float f32x4 __attribute__((ext_vector_type(4)));

__device__ __forceinline__ float bf2f(bf16 x){ return __bfloat162float(x); }
__device__ __forceinline__ bf16 f2bf(float x){ return __float2bfloat16(x); }
__device__ __forceinline__ unsigned short bfbits(float x){ bf16 b = f2bf(x); return *(unsigned short*)&b; }
__device__ __forceinline__ float bits2f(unsigned short u){ bf16 b = *(bf16*)&u; return __bfloat162float(b); }

#define MFMA16 __builtin_amdgcn_mfma_f32_16x16x32_bf16

// ---------------------------------------------------------------------------
// causal convs + stack + @w_val + bias + sinusoidal PE -> h [B,W,F,D]
// ---------------------------------------------------------------------------
__global__ __launch_bounds__(256) void embed_kernel(
    const float* __restrict__ x,
    const float* __restrict__ w1, const float* __restrict__ b1,
    const float* __restrict__ w2, const float* __restrict__ b2,
    const float* __restrict__ w3, const float* __restrict__ b3,
    const float* __restrict__ wval, const float* __restrict__ bval,
    float* __restrict__ h)
{
    int bw = blockIdx.x;               // b*W + w
    int b = bw >> 8, w = bw & 255;
    int tid = threadIdx.x;
    __shared__ float s[FF][4];
    if (tid < 64) {
        int f = tid >> 2, t = tid & 3;
        const float* xb = x + (size_t)b*WW*FF + f;
        float v;
        if (t == 0) {
            v = xb[(size_t)w*FF];
        } else if (t == 1) {
            float acc = b1[f];
            #pragma unroll
            for (int kk = 0; kk < 4; kk++) { int t0 = w - (3-kk); if (t0 >= 0) acc += w1[f*4+kk]*xb[(size_t)t0*FF]; }
            v = acc;
        } else if (t == 2) {
            float acc = b2[f];
            #pragma unroll
            for (int kk = 0; kk < 8; kk++) { int t0 = w - (7-kk)*2; if (t0 >= 0) acc += w2[f*8+kk]*xb[(size_t)t0*FF]; }
            v = acc;
        } else {
            float acc = b3[f];
            #pragma unroll
            for (int kk = 0; kk < 16; kk++) { int t0 = w - (15-kk)*3; if (t0 >= 0) acc += w3[f*16+kk]*xb[(size_t)t0*FF]; }
            v = acc;
        }
        s[f][t] = v;
    }
    __syncthreads();
    #pragma unroll
    for (int r = 0; r < 8; r++) {
        int lin = r*256 + tid;
        int f = lin >> 7, d = lin & 127;
        float div = expf(-(float)(d & ~1) * LN10K_D);
        float arg = (float)w * div;
        float pe = (d & 1) ? cosf(arg) : sinf(arg);
        float e = bval[d] + pe;
        #pragma unroll
        for (int t = 0; t < 4; t++) e += s[f][t]*wval[t*128 + d];
        h[((size_t)bw*FF + f)*128 + d] = e;
    }
}

// ---------------------------------------------------------------------------
// transpose+convert weights to bf16
// ---------------------------------------------------------------------------
__global__ __launch_bounds__(256) void convert_w(
    const float* __restrict__ wqkv, const float* __restrict__ wout,
    const float* __restrict__ wh,
    bf16* __restrict__ wqkvT, bf16* __restrict__ woutT, bf16* __restrict__ whT)
{
    int idx = blockIdx.x*256 + threadIdx.x;
    const int T1 = 4*3072*128;
    const int T2 = 4*128*1024;
    const int T3 = 16*2048;
    if (idx < T1) {
        int l = idx / (3072*128);
        int rem = idx % (3072*128);
        int n = rem / 128, kk2 = rem % 128;
        wqkvT[idx] = f2bf(wqkv[((size_t)l*128 + kk2)*3072 + n]);
    } else if (idx < T1 + T2) {
        int j = idx - T1;
        int l = j / (128*1024);
        int rem = j % (128*1024);
        int n = rem / 1024, kk2 = rem % 1024;
        woutT[j] = f2bf(wout[((size_t)l*1024 + kk2)*128 + n]);
    } else if (idx < T1 + T2 + T3) {
        int j = idx - T1 - T2;
        int n = j >> 11, kk2 = j & 2047;
        whT[j] = f2bf(wh[(size_t)kk2*16 + n]);
    }
}

// ---------------------------------------------------------------------------
// LayerNorm h(fp32) -> hn(bf16)
// ---------------------------------------------------------------------------
__global__ __launch_bounds__(256) void ln_kernel(
    const float* __restrict__ h, const float* __restrict__ g,
    const float* __restrict__ b, bf16* __restrict__ hn)
{
    int tid = threadIdx.x;
    int tok = blockIdx.x*16 + (tid>>4);
    int sub = tid & 15;
    const float* hr = h + (size_t)tok*128 + sub*8;
    float xv[8];
    *(float4*)&xv[0] = *(const float4*)hr;
    *(float4*)&xv[4] = *(const float4*)(hr+4);
    float s1 = 0.f, s2 = 0.f;
    #pragma unroll
    for (int e = 0; e < 8; e++) { s1 += xv[e]; s2 += xv[e]*xv[e]; }
    #pragma unroll
    for (int m = 1; m < 16; m <<= 1) {
        s1 += __shfl_xor(s1, m, 64);
        s2 += __shfl_xor(s2, m, 64);
    }
    float mean = s1*INV_D;
    float var  = s2*INV_D - mean*mean;
    float rs = rsqrtf(var + 1e-5f);
    union { uint4 u; unsigned short sh[8]; } o;
    #pragma unroll
    for (int e = 0; e < 8; e++) {
        int d = sub*8 + e;
        o.sh[e] = bfbits((xv[e]-mean)*rs*g[d] + b[d]);
    }
    *(uint4*)(hn + (size_t)tok*128 + sub*8) = o.u;
}

// ---------------------------------------------------------------------------
// QKV GEMM, MFMA.  Direct global frag loads; epilogue transposed through
// per-wave LDS so all global stores are uint4 (128B/row segments).
// ---------------------------------------------------------------------------
__global__ __launch_bounds__(256) void qkv_mfma(
    const bf16* __restrict__ hn, const bf16* __restrict__ wT,
    bf16* __restrict__ q, bf16* __restrict__ k, bf16* __restrict__ v,
    int tokbase)
{
    __shared__ __align__(16) unsigned short Cs[4][64][72];   // 36,864 B
    int tid = threadIdx.x;
    int lane = tid & 63, wave = tid >> 6;
    int quad = lane >> 4, l16 = lane & 15;
    int wm = wave >> 1, wn = wave & 1;
    int m0 = blockIdx.x * 128, n0 = blockIdx.y * 128;

    f32x4 acc[4][4];
    #pragma unroll
    for (int a = 0; a < 4; a++)
        #pragma unroll
        for (int c = 0; c < 4; c++) acc[a][c] = 0.f;

    #pragma unroll
    for (int kt = 0; kt < 4; kt++) {
        int ko = kt*32 + quad*8;
        bf16x8 af[4], bfr[4];
        #pragma unroll
        for (int tm = 0; tm < 4; tm++)
            af[tm] = *(const bf16x8*)(hn + (size_t)(tokbase + m0 + wm*64 + tm*16 + l16)*128 + ko);
        #pragma unroll
        for (int tn = 0; tn < 4; tn++)
            bfr[tn] = *(const bf16x8*)(wT + (size_t)(n0 + wn*64 + tn*16 + l16)*128 + ko);
        #pragma unroll
        for (int tm = 0; tm < 4; tm++)
            #pragma unroll
            for (int tn = 0; tn < 4; tn++)
                acc[tm][tn] = MFMA16(af[tm], bfr[tn], acc[tm][tn], 0, 0, 0);
    }

    bf16* dst; int nrel; float scl;
    if (n0 < 1024)      { dst = q; nrel = n0;        scl = SCALE; }
    else if (n0 < 2048) { dst = k; nrel = n0 - 1024; scl = 1.0f; }
    else                { dst = v; nrel = n0 - 2048; scl = 1.0f; }

    // stage C tile (per-wave private; no barrier needed)
    #pragma unroll
    for (int tm = 0; tm < 4; tm++)
        #pragma unroll
        for (int tn = 0; tn < 4; tn++)
            #pragma unroll
            for (int r = 0; r < 4; r++)
                Cs[wave][tm*16 + quad*4 + r][tn*16 + l16] = bfbits(acc[tm][tn][r]*scl);

    // coalesced store: 8 rows x 128B per instruction
    #pragma unroll
    for (int p = 0; p < 8; p++) {
        int row = p*8 + (lane >> 3);
        int c8  = (lane & 7)*8;
        uint4 val = *(const uint4*)&Cs[wave][row][c8];
        size_t gaddr = (size_t)(m0 + wm*64 + row)*1024 + nrel + wn*64 + c8;
        *(uint4*)(dst + gaddr) = val;
    }
}

// ---------------------------------------------------------------------------
// temporal attention, MFMA.  ONE block per (bl,f,h); 4 sequential 64-row
// i-passes so K/V stay L2-hot on one XCD.  Pure write of o (runs BEFORE
// vattn).  Epilogue staged through LDS -> uint4 stores.
// ---------------------------------------------------------------------------
__global__ __launch_bounds__(256) void tattn_mfma(
    const bf16* __restrict__ q, const bf16* __restrict__ k, const bf16* __restrict__ v,
    bf16* __restrict__ o)
{
    __shared__ __align__(16) unsigned short VsT[128*72];      // 18,432 B (Os overlay)
    __shared__ __align__(16) unsigned short Ps[4][16][264];   // 33,792 B
    unsigned short* Os = VsT;                                  // [64][136] overlay

    int bx = blockIdx.x;
    int hh = bx & 7, f = (bx>>3) & 15, bl = bx >> 7;
    int tid = threadIdx.x;
    int lane = tid & 63, wave = tid >> 6;
    int quad = lane >> 4, l16 = lane & 15;

    size_t base = ((size_t)(bl*WW)*FF + f)*1024 + (size_t)hh*128;
    int rr = tid >> 4, cc = (tid & 15)*8;

    #pragma unroll 1
    for (int pass = 0; pass < 4; pass++) {
        int i0 = pass*64;

        // Q frags (A-layout: m=l16, k=quad*8+e)
        bf16x8 af[4];
        {
            size_t qa = base + (size_t)(i0 + wave*16 + l16)*16384;
            #pragma unroll
            for (int kt = 0; kt < 4; kt++)
                af[kt] = *(const bf16x8*)(q + qa + kt*32 + quad*8);
        }

        // phase 1: S = Q K^T (K frags direct global, L2-hot after pass 0)
        f32x4 s_acc[16];
        #pragma unroll
        for (int t = 0; t < 16; t++) s_acc[t] = 0.f;
        #pragma unroll 4
        for (int t = 0; t < 16; t++) {
            size_t ja = base + (size_t)(t*16 + l16)*16384;
            #pragma unroll
            for (int kt = 0; kt < 4; kt++) {
                bf16x8 kf = *(const bf16x8*)(k + ja + kt*32 + quad*8);
                s_acc[t] = MFMA16(af[kt], kf, s_acc[t], 0, 0, 0);
            }
        }

        // phase 2: softmax (rows quad*4+r, cols t*16+l16)
        float mx[4], sm[4], inv[4];
        #pragma unroll
        for (int r = 0; r < 4; r++) mx[r] = -1e30f;
        #pragma unroll
        for (int t = 0; t < 16; t++)
            #pragma unroll
            for (int r = 0; r < 4; r++) mx[r] = fmaxf(mx[r], s_acc[t][r]);
        #pragma unroll
        for (int m = 1; m < 16; m <<= 1)
            #pragma unroll
            for (int r = 0; r < 4; r++) mx[r] = fmaxf(mx[r], __shfl_xor(mx[r], m, 64));
        #pragma unroll
        for (int r = 0; r < 4; r++) sm[r] = 0.f;
        #pragma unroll
        for (int t = 0; t < 16; t++)
            #pragma unroll
            for (int r = 0; r < 4; r++) {
                float p = __expf(s_acc[t][r] - mx[r]);
                s_acc[t][r] = p;
                sm[r] += p;
            }
        #pragma unroll
        for (int m = 1; m < 16; m <<= 1)
            #pragma unroll
            for (int r = 0; r < 4; r++) sm[r] += __shfl_xor(sm[r], m, 64);
        #pragma unroll
        for (int r = 0; r < 4; r++) inv[r] = 1.f / sm[r];

        // write P to per-wave LDS (private; lgkmcnt handles within-wave order)
        #pragma unroll
        for (int t = 0; t < 16; t++)
            #pragma unroll
            for (int r = 0; r < 4; r++)
                Ps[wave][quad*4+r][t*16+l16] = bfbits(s_acc[t][r]);

        // phase 3: O = P @ V over 4 j-tiles, V^T staged with rotation swizzle
        f32x4 oacc[8];
        #pragma unroll
        for (int t = 0; t < 8; t++) oacc[t] = 0.f;

        for (int jt = 0; jt < 4; jt++) {
            __syncthreads();   // prior VsT/Os reads complete
            #pragma unroll
            for (int r4 = 0; r4 < 4; r4++) {
                int j = r4*16 + rr;
                union { uint4 u; unsigned short sh[8]; } uu;
                uu.u = *(const uint4*)(v + base + (size_t)(jt*64 + j)*16384 + cc);
                int col = (j + ((tid & 7) << 3)) & 63;
                #pragma unroll
                for (int e = 0; e < 8; e++)
                    VsT[(cc + e)*72 + col] = uu.sh[e];
            }
            __syncthreads();
            #pragma unroll
            for (int kt2 = 0; kt2 < 2; kt2++) {
                int kbase = kt2*32 + quad*8;
                bf16x8 pf = *(const bf16x8*)&Ps[wave][l16][jt*64 + kbase];
                #pragma unroll
                for (int t = 0; t < 8; t++) {
                    int d = t*16 + l16;
                    int colstart = (kbase + (((d>>3)&7) << 3)) & 63;
                    bf16x8 vf = *(const bf16x8*)&VsT[d*72 + colstart];
                    oacc[t] = MFMA16(pf, vf, oacc[t], 0, 0, 0);
                }
            }
        }

        // epilogue: stage O (bf16) into Os overlay, then coalesced stores
        __syncthreads();   // all VsT reads done
        #pragma unroll
        for (int t = 0; t < 8; t++)
            #pragma unroll
            for (int r = 0; r < 4; r++)
                Os[(wave*16 + quad*4 + r)*136 + t*16 + l16] = bfbits(oacc[t][r]*inv[r]);
        __syncthreads();
        #pragma unroll
        for (int r4 = 0; r4 < 4; r4++) {
            int row = r4*4 + quad;
            uint4 val = *(const uint4*)&Os[(wave*16 + row)*136 + l16*8];
            size_t gaddr = base + (size_t)(i0 + wave*16 + row)*16384 + l16*8;
            *(uint4*)(o + gaddr) = val;
        }
    }
}

// ---------------------------------------------------------------------------
// variable attention, MFMA.  One block per (bl,w); o += result via
// cooperative vectorized RMW (runs AFTER tattn).
// ---------------------------------------------------------------------------
__global__ __launch_bounds__(256) void vattn_mfma(
    const bf16* __restrict__ q, const bf16* __restrict__ k, const bf16* __restrict__ v,
    bf16* __restrict__ o)
{
    __shared__ __align__(16) unsigned short VsT[1024*24];   // 49,152 B (Os overlay)
    __shared__ __align__(16) unsigned short Ps[4][16][24];  //  3,072 B
    unsigned short* Os = VsT;                                // [16][1040] overlay

    int tid = threadIdx.x;
    int lane = tid & 63, wave = tid >> 6, quad = lane >> 4, l16 = lane & 15;
    size_t base = (size_t)blockIdx.x * 16384;

    // stage V^T for all heads: VsT[d][j] = V[j][d]
    #pragma unroll
    for (int p = 0; p < 8; p++) {
        int lin = p*256 + tid;
        int j = lin >> 7, d0 = (lin & 127)*8;
        union { uint4 u; unsigned short sh[8]; } uu;
        uu.u = *(const uint4*)(v + base + (size_t)j*1024 + d0);
        #pragma unroll
        for (int e = 0; e < 8; e++) VsT[(d0+e)*24 + j] = uu.sh[e];
    }
    __syncthreads();

    bf16x8 zf = {0,0,0,0,0,0,0,0};
    f32x4 oa[2][8];
    #pragma unroll
    for (int hi = 0; hi < 2; hi++) {
        int hh = wave*2 + hi;
        size_t hb = base + hh*128;

        f32x4 s = {0.f,0.f,0.f,0.f};
        #pragma unroll
        for (int kt = 0; kt < 4; kt++) {
            bf16x8 qf = *(const bf16x8*)(q + hb + (size_t)l16*1024 + kt*32 + quad*8);
            bf16x8 kf = *(const bf16x8*)(k + hb + (size_t)l16*1024 + kt*32 + quad*8);
            s = MFMA16(qf, kf, s, 0, 0, 0);
        }
        float p[4];
        #pragma unroll
        for (int r = 0; r < 4; r++) {
            float mxv = s[r];
            #pragma unroll
            for (int m = 1; m < 16; m <<= 1) mxv = fmaxf(mxv, __shfl_xor(mxv, m, 64));
            float e = __expf(s[r] - mxv);
            float smv = e;
            #pragma unroll
            for (int m = 1; m < 16; m <<= 1) smv += __shfl_xor(smv, m, 64);
            p[r] = e / smv;
        }
        // per-wave private P buffer
        #pragma unroll
        for (int r = 0; r < 4; r++) Ps[wave][quad*4+r][l16] = bfbits(p[r]);

        bf16x8 pf = zf;
        if (quad < 2) pf = *(const bf16x8*)&Ps[wave][l16][quad*8];
        #pragma unroll
        for (int dt = 0; dt < 8; dt++) oa[hi][dt] = 0.f;
        #pragma unroll
        for (int dt = 0; dt < 8; dt++) {
            bf16x8 vf = zf;
            if (quad < 2) vf = *(const bf16x8*)&VsT[(size_t)(hh*128 + dt*16 + l16)*24 + quad*8];
            oa[hi][dt] = MFMA16(pf, vf, oa[hi][dt], 0, 0, 0);
        }
    }

    // stage both heads' output into Os overlay (rows = f, cols = h*128+d)
    __syncthreads();   // all VsT reads done
    #pragma unroll
    for (int hi = 0; hi < 2; hi++) {
        int hh = wave*2 + hi;
        #pragma unroll
        for (int dt = 0; dt < 8; dt++)
            #pragma unroll
            for (int r = 0; r < 4; r++)
                Os[(quad*4 + r)*1040 + hh*128 + dt*16 + l16] = bfbits(oa[hi][dt][r]);
    }
    __syncthreads();

    // cooperative vectorized RMW: o += Os
    #pragma unroll
    for (int u = 0; u < 8; u++) {
        int lin = u*256 + tid;
        int fr = lin >> 7, dc = (lin & 127)*8;
        size_t ga = base + (size_t)fr*1024 + dc;
        union { uint4 u4; unsigned short sh[8]; } a, bsh, w;
        a.u4   = *(const uint4*)(o + ga);
        bsh.u4 = *(const uint4*)&Os[fr*1040 + dc];
        #pragma unroll
        for (int e = 0; e < 8; e++)
            w.sh[e] = bfbits(bits2f(a.sh[e]) + bits2f(bsh.sh[e]));
        *(uint4*)(o + ga) = w.u4;
    }
}

// ---------------------------------------------------------------------------
// out-projection, MFMA, LDS-free.  h += o @ woutT^T + bias (fp32 64B RMW ok).
// ---------------------------------------------------------------------------
__global__ __launch_bounds__(256) void proj_mfma(
    const bf16* __restrict__ o, const bf16* __restrict__ woT,
    const float* __restrict__ bo, float* __restrict__ h, int tokbase)
{
    int tid = threadIdx.x;
    int lane = tid & 63, wave = tid >> 6;
    int quad = lane >> 4, l16 = lane & 15;
    int wm = wave >> 1, wn = wave & 1;
    int m0 = blockIdx.x * 128;

    f32x4 acc[4][4];
    #pragma unroll
    for (int a = 0; a < 4; a++)
        #pragma unroll
        for (int c = 0; c < 4; c++) acc[a][c] = 0.f;

    for (int kc = 0; kc < 32; kc++) {
        int ko = kc*32 + quad*8;
        bf16x8 af[4], bfr[4];
        #pragma unroll
        for (int tm = 0; tm < 4; tm++)
            af[tm] = *(const bf16x8*)(o + (size_t)(m0 + wm*64 + tm*16 + l16)*1024 + ko);
        #pragma unroll
        for (int tn = 0; tn < 4; tn++)
            bfr[tn] = *(const bf16x8*)(woT + (size_t)(wn*64 + tn*16 + l16)*1024 + ko);
        #pragma unroll
        for (int tm = 0; tm < 4; tm++)
            #pragma unroll
            for (int tn = 0; tn < 4; tn++)
                acc[tm][tn] = MFMA16(af[tm], bfr[tn], acc[tm][tn], 0, 0, 0);
    }

    #pragma unroll
    for (int tm = 0; tm < 4; tm++)
        #pragma unroll
        for (int tn = 0; tn < 4; tn++) {
            int gcol = wn*64 + tn*16 + l16;
            #pragma unroll
            for (int r = 0; r < 4; r++) {
                int grow = m0 + wm*64 + tm*16 + quad*4 + r;
                size_t idx = (size_t)(tokbase + grow)*128 + gcol;
                h[idx] += acc[tm][tn][r] + bo[gcol];
            }
        }
}

// ---------------------------------------------------------------------------
// head, MFMA: out[2048,16] = h[2048,2048]@whT^T + bh
// ---------------------------------------------------------------------------
__global__ __launch_bounds__(256) void head_mfma(
    const float* __restrict__ h, const bf16* __restrict__ whT,
    const float* __restrict__ bh, float* __restrict__ out)
{
    __shared__ float sred[4][16][17];
    int tid = threadIdx.x;
    int lane = tid & 63, wave = tid >> 6, quad = lane >> 4, l16 = lane & 15;
    int bw0 = blockIdx.x * 16;
    const float* hrow = h + (size_t)(bw0 + l16)*2048 + wave*512;
    const bf16* wrow  = whT + (size_t)l16*2048 + wave*512;

    f32x4 acc = {0.f,0.f,0.f,0.f};
    #pragma unroll 4
    for (int kc = 0; kc < 16; kc++) {
        int ko = kc*32 + quad*8;
        float4 a0 = *(const float4*)(hrow + ko);
        float4 a1 = *(const float4*)(hrow + ko + 4);
        union { bf16x8 v; unsigned short sh[8]; } ua;
        ua.sh[0]=bfbits(a0.x); ua.sh[1]=bfbits(a0.y); ua.sh[2]=bfbits(a0.z); ua.sh[3]=bfbits(a0.w);
        ua.sh[4]=bfbits(a1.x); ua.sh[5]=bfbits(a1.y); ua.sh[6]=bfbits(a1.z); ua.sh[7]=bfbits(a1.w);
        bf16x8 bv = *(const bf16x8*)(wrow + ko);
        acc = MFMA16(ua.v, bv, acc, 0, 0, 0);
    }
    #pragma unroll
    for (int r = 0; r < 4; r++) sred[wave][quad*4+r][l16] = acc[r];
    __syncthreads();
    int i = tid >> 4, n = tid & 15;
    float s = bh[n] + sred[0][i][n] + sred[1][i][n] + sred[2][i][n] + sred[3][i][n];
    out[(size_t)(bw0 + i)*16 + n] = s;
}

// ---------------------------------------------------------------------------
extern "C" void kernel_launch(void* const* d_in, const int* in_sizes, int n_in,
                              void* d_out, int out_size, void* d_ws, size_t ws_size,
                              hipStream_t stream)
{
    const float* x    = (const float*)d_in[0];
    const float* w1   = (const float*)d_in[1];
    const float* b1   = (const float*)d_in[2];
    const float* w2   = (const float*)d_in[3];
    const float* b2   = (const float*)d_in[4];
    const float* w3   = (const float*)d_in[5];
    const float* b3   = (const float*)d_in[6];
    const float* wval = (const float*)d_in[7];
    const float* bval = (const float*)d_in[8];
    const float* lng  = (const float*)d_in[9];
    const float* lnb  = (const float*)d_in[10];
    const float* wqkv = (const float*)d_in[11];
    const float* wout = (const float*)d_in[12];
    const float* bout = (const float*)d_in[13];
    const float* wh   = (const float*)d_in[14];
    const float* bh   = (const float*)d_in[15];
    float* out = (float*)d_out;

    char* ws = (char*)d_ws;
    bf16*  wqkvT = (bf16*)ws;                       // 3,145,728 B
    bf16*  woutT = (bf16*)(ws + 3145728);           // 1,048,576 B
    bf16*  whT   = (bf16*)(ws + 4194304);           //    65,536 B
    float* h     = (float*)(ws + 4259840);          // 16,777,216 B
    bf16*  hn    = (bf16*)(ws + 21037056);          //  8,388,608 B
    const size_t qoff = 29425664ull;

    int NBL = 1;
    if      (ws_size >= qoff + 8ull*4ull*8388608ull) NBL = 8;
    else if (ws_size >= qoff + 4ull*4ull*8388608ull) NBL = 4;
    else if (ws_size >= qoff + 2ull*4ull*8388608ull) NBL = 2;
    size_t bsz = (size_t)NBL * 8388608ull;
    bf16* q  = (bf16*)(ws + qoff);
    bf16* kk = (bf16*)(ws + qoff + bsz);
    bf16* vv = (bf16*)(ws + qoff + 2*bsz);
    bf16* oo = (bf16*)(ws + qoff + 3*bsz);

    convert_w<<<8320, 256, 0, stream>>>(wqkv, wout, wh, wqkvT, woutT, whT);
    embed_kernel<<<BB*WW, 256, 0, stream>>>(x, w1,b1, w2,b2, w3,b3, wval, bval, h);

    for (int l = 0; l < 4; l++) {
        const bf16* wqT_l = wqkvT + (size_t)l*3072*128;
        const bf16* woT_l = woutT + (size_t)l*128*1024;
        const float* bo_l = bout + l*128;
        ln_kernel<<<NTOK/16, 256, 0, stream>>>(h, lng + l*128, lnb + l*128, hn);
        for (int bb = 0; bb < BB; bb += NBL) {
            int tokbase = bb*WW*FF;
            qkv_mfma<<<dim3(NBL*32, 24), 256, 0, stream>>>(
                hn, wqT_l, q, kk, vv, tokbase);
            tattn_mfma<<<NBL*FF*HH, 256, 0, stream>>>(q, kk, vv, oo);   // writes o
            vattn_mfma<<<NBL*WW, 256, 0, stream>>>(q, kk, vv, oo);      // o += ov
            proj_mfma<<<NBL*32, 256, 0, stream>>>(oo, woT_l, bo_l, h, tokbase);
        }
    }

    head_mfma<<<BB*WW/16, 256, 0, stream>>>(h, whT, bh, out);
}

// Round 5
// 1763.883 us; speedup vs baseline: 5.6578x; 1.4869x over previous
//
#include <hip/hip_runtime.h>
#include <hip/hip_bf16.h>
#include <math.h>

#define BB 8
#define WW 256
#define FF 16
#define DD 128
#define HH 8
#define NTOK (BB*WW*FF)        // 32768
#define SCALE 0.08838834764831845f
#define INV_D (1.0f/128.0f)
#define LN10K_D 0.07195578415606394f   // ln(10000)/128

typedef __hip_bfloat16 bf16;
typedef short bf16x8 __attribute__((ext_vector_type(8)));   // 8 bf16 = 4 VGPRs
typedef float f32x4 __attribute__((ext_vector_type(4)));

__device__ __forceinline__ float bf2f(bf16 x){ return __bfloat162float(x); }
__device__ __forceinline__ bf16 f2bf(float x){ return __float2bfloat16(x); }
__device__ __forceinline__ unsigned short bfbits(float x){ bf16 b = f2bf(x); return *(unsigned short*)&b; }
__device__ __forceinline__ float bits2f(unsigned short u){ bf16 b = *(bf16*)&u; return __bfloat162float(b); }

#define MFMA16 __builtin_amdgcn_mfma_f32_16x16x32_bf16

// ---------------------------------------------------------------------------
// causal convs + stack + @w_val + bias + sinusoidal PE -> h [B,W,F,D]
// ---------------------------------------------------------------------------
__global__ __launch_bounds__(256) void embed_kernel(
    const float* __restrict__ x,
    const float* __restrict__ w1, const float* __restrict__ b1,
    const float* __restrict__ w2, const float* __restrict__ b2,
    const float* __restrict__ w3, const float* __restrict__ b3,
    const float* __restrict__ wval, const float* __restrict__ bval,
    float* __restrict__ h)
{
    int bw = blockIdx.x;               // b*W + w
    int b = bw >> 8, w = bw & 255;
    int tid = threadIdx.x;
    __shared__ float s[FF][4];
    if (tid < 64) {
        int f = tid >> 2, t = tid & 3;
        const float* xb = x + (size_t)b*WW*FF + f;
        float v;
        if (t == 0) {
            v = xb[(size_t)w*FF];
        } else if (t == 1) {
            float acc = b1[f];
            #pragma unroll
            for (int kk = 0; kk < 4; kk++) { int t0 = w - (3-kk); if (t0 >= 0) acc += w1[f*4+kk]*xb[(size_t)t0*FF]; }
            v = acc;
        } else if (t == 2) {
            float acc = b2[f];
            #pragma unroll
            for (int kk = 0; kk < 8; kk++) { int t0 = w - (7-kk)*2; if (t0 >= 0) acc += w2[f*8+kk]*xb[(size_t)t0*FF]; }
            v = acc;
        } else {
            float acc = b3[f];
            #pragma unroll
            for (int kk = 0; kk < 16; kk++) { int t0 = w - (15-kk)*3; if (t0 >= 0) acc += w3[f*16+kk]*xb[(size_t)t0*FF]; }
            v = acc;
        }
        s[f][t] = v;
    }
    __syncthreads();
    #pragma unroll
    for (int r = 0; r < 8; r++) {
        int lin = r*256 + tid;
        int f = lin >> 7, d = lin & 127;
        float div = expf(-(float)(d & ~1) * LN10K_D);
        float arg = (float)w * div;
        float pe = (d & 1) ? cosf(arg) : sinf(arg);
        float e = bval[d] + pe;
        #pragma unroll
        for (int t = 0; t < 4; t++) e += s[f][t]*wval[t*128 + d];
        h[((size_t)bw*FF + f)*128 + d] = e;
    }
}

// ---------------------------------------------------------------------------
// transpose+convert weights to bf16
// ---------------------------------------------------------------------------
__global__ __launch_bounds__(256) void convert_w(
    const float* __restrict__ wqkv, const float* __restrict__ wout,
    const float* __restrict__ wh,
    bf16* __restrict__ wqkvT, bf16* __restrict__ woutT, bf16* __restrict__ whT)
{
    int idx = blockIdx.x*256 + threadIdx.x;
    const int T1 = 4*3072*128;
    const int T2 = 4*128*1024;
    const int T3 = 16*2048;
    if (idx < T1) {
        int l = idx / (3072*128);
        int rem = idx % (3072*128);
        int n = rem / 128, kk2 = rem % 128;
        wqkvT[idx] = f2bf(wqkv[((size_t)l*128 + kk2)*3072 + n]);
    } else if (idx < T1 + T2) {
        int j = idx - T1;
        int l = j / (128*1024);
        int rem = j % (128*1024);
        int n = rem / 1024, kk2 = rem % 1024;
        woutT[j] = f2bf(wout[((size_t)l*1024 + kk2)*128 + n]);
    } else if (idx < T1 + T2 + T3) {
        int j = idx - T1 - T2;
        int n = j >> 11, kk2 = j & 2047;
        whT[j] = f2bf(wh[(size_t)kk2*16 + n]);
    }
}

// ---------------------------------------------------------------------------
// LayerNorm h(fp32) -> hn(bf16)
// ---------------------------------------------------------------------------
__global__ __launch_bounds__(256) void ln_kernel(
    const float* __restrict__ h, const float* __restrict__ g,
    const float* __restrict__ b, bf16* __restrict__ hn)
{
    int tid = threadIdx.x;
    int tok = blockIdx.x*16 + (tid>>4);
    int sub = tid & 15;
    const float* hr = h + (size_t)tok*128 + sub*8;
    float xv[8];
    *(float4*)&xv[0] = *(const float4*)hr;
    *(float4*)&xv[4] = *(const float4*)(hr+4);
    float s1 = 0.f, s2 = 0.f;
    #pragma unroll
    for (int e = 0; e < 8; e++) { s1 += xv[e]; s2 += xv[e]*xv[e]; }
    #pragma unroll
    for (int m = 1; m < 16; m <<= 1) {
        s1 += __shfl_xor(s1, m, 64);
        s2 += __shfl_xor(s2, m, 64);
    }
    float mean = s1*INV_D;
    float var  = s2*INV_D - mean*mean;
    float rs = rsqrtf(var + 1e-5f);
    union { uint4 u; unsigned short sh[8]; } o;
    #pragma unroll
    for (int e = 0; e < 8; e++) {
        int d = sub*8 + e;
        o.sh[e] = bfbits((xv[e]-mean)*rs*g[d] + b[d]);
    }
    *(uint4*)(hn + (size_t)tok*128 + sub*8) = o.u;
}

// ---------------------------------------------------------------------------
// QKV GEMM, MFMA.  Direct global frag loads; LDS-transposed coalesced stores.
// ---------------------------------------------------------------------------
__global__ __launch_bounds__(256) void qkv_mfma(
    const bf16* __restrict__ hn, const bf16* __restrict__ wT,
    bf16* __restrict__ q, bf16* __restrict__ k, bf16* __restrict__ v,
    int tokbase)
{
    __shared__ __align__(16) unsigned short Cs[4][64][72];   // 36,864 B
    int tid = threadIdx.x;
    int lane = tid & 63, wave = tid >> 6;
    int quad = lane >> 4, l16 = lane & 15;
    int wm = wave >> 1, wn = wave & 1;
    int m0 = blockIdx.x * 128, n0 = blockIdx.y * 128;

    f32x4 acc[4][4];
    #pragma unroll
    for (int a = 0; a < 4; a++)
        #pragma unroll
        for (int c = 0; c < 4; c++) acc[a][c] = 0.f;

    #pragma unroll
    for (int kt = 0; kt < 4; kt++) {
        int ko = kt*32 + quad*8;
        bf16x8 af[4], bfr[4];
        #pragma unroll
        for (int tm = 0; tm < 4; tm++)
            af[tm] = *(const bf16x8*)(hn + (size_t)(tokbase + m0 + wm*64 + tm*16 + l16)*128 + ko);
        #pragma unroll
        for (int tn = 0; tn < 4; tn++)
            bfr[tn] = *(const bf16x8*)(wT + (size_t)(n0 + wn*64 + tn*16 + l16)*128 + ko);
        #pragma unroll
        for (int tm = 0; tm < 4; tm++)
            #pragma unroll
            for (int tn = 0; tn < 4; tn++)
                acc[tm][tn] = MFMA16(af[tm], bfr[tn], acc[tm][tn], 0, 0, 0);
    }

    bf16* dst; int nrel; float scl;
    if (n0 < 1024)      { dst = q; nrel = n0;        scl = SCALE; }
    else if (n0 < 2048) { dst = k; nrel = n0 - 1024; scl = 1.0f; }
    else                { dst = v; nrel = n0 - 2048; scl = 1.0f; }

    #pragma unroll
    for (int tm = 0; tm < 4; tm++)
        #pragma unroll
        for (int tn = 0; tn < 4; tn++)
            #pragma unroll
            for (int r = 0; r < 4; r++)
                Cs[wave][tm*16 + quad*4 + r][tn*16 + l16] = bfbits(acc[tm][tn][r]*scl);

    #pragma unroll
    for (int p = 0; p < 8; p++) {
        int row = p*8 + (lane >> 3);
        int c8  = (lane & 7)*8;
        uint4 val = *(const uint4*)&Cs[wave][row][c8];
        size_t gaddr = (size_t)(m0 + wm*64 + row)*1024 + nrel + wn*64 + c8;
        *(uint4*)(dst + gaddr) = val;
    }
}

// ---------------------------------------------------------------------------
// temporal attention, MFMA, ONLINE SOFTMAX (flash).  One block per (bl,f,h);
// 4 sequential 64-row i-passes; per pass, 4 j-tiles of 64 with running m/l
// and O-rescale -- S never fully materialized -> no register spill.
// Pure coalesced write of o.
// ---------------------------------------------------------------------------
__global__ __launch_bounds__(256) void tattn_mfma(
    const bf16* __restrict__ q, const bf16* __restrict__ k, const bf16* __restrict__ v,
    bf16* __restrict__ o)
{
    __shared__ __align__(16) unsigned short VsT[128*72];   // 18,432 B (Os overlay)
    __shared__ __align__(16) unsigned short Ps[4][16][72]; //  9,216 B
    unsigned short* Os = VsT;                               // [64][136] = 17,408 B

    int bx = blockIdx.x;
    int hh = bx & 7, f = (bx>>3) & 15, bl = bx >> 7;
    int tid = threadIdx.x;
    int lane = tid & 63, wave = tid >> 6;
    int quad = lane >> 4, l16 = lane & 15;

    size_t base = ((size_t)(bl*WW)*FF + f)*1024 + (size_t)hh*128;
    int rr = tid >> 4, cc = (tid & 15)*8;

    #pragma unroll 1
    for (int pass = 0; pass < 4; pass++) {
        int i0 = pass*64;

        bf16x8 af[4];
        {
            size_t qa = base + (size_t)(i0 + wave*16 + l16)*16384;
            #pragma unroll
            for (int kt = 0; kt < 4; kt++)
                af[kt] = *(const bf16x8*)(q + qa + kt*32 + quad*8);
        }

        f32x4 oacc[8];
        #pragma unroll
        for (int t = 0; t < 8; t++) oacc[t] = 0.f;
        float m_run[4], l_run[4];
        #pragma unroll
        for (int r = 0; r < 4; r++) { m_run[r] = -1e30f; l_run[r] = 0.f; }

        #pragma unroll 1
        for (int jt = 0; jt < 4; jt++) {
            __syncthreads();   // prior VsT/Os reads complete
            // stage V^T tile (64 j) with rotation swizzle
            #pragma unroll
            for (int r4 = 0; r4 < 4; r4++) {
                int j = r4*16 + rr;
                union { uint4 u; unsigned short sh[8]; } uu;
                uu.u = *(const uint4*)(v + base + (size_t)(jt*64 + j)*16384 + cc);
                int col = (j + ((tid & 7) << 3)) & 63;
                #pragma unroll
                for (int e = 0; e < 8; e++)
                    VsT[(cc + e)*72 + col] = uu.sh[e];
            }
            __syncthreads();

            // S tile = Q K^T for 64 j (4 n-tiles)
            f32x4 st[4];
            #pragma unroll
            for (int t = 0; t < 4; t++) st[t] = 0.f;
            #pragma unroll
            for (int t = 0; t < 4; t++) {
                size_t ja = base + (size_t)(jt*64 + t*16 + l16)*16384;
                #pragma unroll
                for (int kt = 0; kt < 4; kt++) {
                    bf16x8 kf = *(const bf16x8*)(k + ja + kt*32 + quad*8);
                    st[t] = MFMA16(af[kt], kf, st[t], 0, 0, 0);
                }
            }

            // online softmax update (rows quad*4+r, cols t*16+l16)
            float tmax[4];
            #pragma unroll
            for (int r = 0; r < 4; r++) tmax[r] = fmaxf(fmaxf(st[0][r], st[1][r]), fmaxf(st[2][r], st[3][r]));
            #pragma unroll
            for (int m = 1; m < 16; m <<= 1)
                #pragma unroll
                for (int r = 0; r < 4; r++) tmax[r] = fmaxf(tmax[r], __shfl_xor(tmax[r], m, 64));
            float alpha[4], rs[4];
            #pragma unroll
            for (int r = 0; r < 4; r++) {
                float mnew = fmaxf(m_run[r], tmax[r]);
                alpha[r] = __expf(m_run[r] - mnew);
                m_run[r] = mnew;
                rs[r] = 0.f;
            }
            #pragma unroll
            for (int t = 0; t < 4; t++)
                #pragma unroll
                for (int r = 0; r < 4; r++) {
                    float p = __expf(st[t][r] - m_run[r]);
                    st[t][r] = p;
                    rs[r] += p;
                }
            #pragma unroll
            for (int m = 1; m < 16; m <<= 1)
                #pragma unroll
                for (int r = 0; r < 4; r++) rs[r] += __shfl_xor(rs[r], m, 64);
            #pragma unroll
            for (int r = 0; r < 4; r++) l_run[r] = l_run[r]*alpha[r] + rs[r];
            #pragma unroll
            for (int t = 0; t < 8; t++)
                #pragma unroll
                for (int r = 0; r < 4; r++) oacc[t][r] *= alpha[r];

            // P tile -> per-wave LDS (wave-private; lgkmcnt orders wr->rd)
            #pragma unroll
            for (int t = 0; t < 4; t++)
                #pragma unroll
                for (int r = 0; r < 4; r++)
                    Ps[wave][quad*4+r][t*16+l16] = bfbits(st[t][r]);

            // PV for this tile
            #pragma unroll
            for (int kt2 = 0; kt2 < 2; kt2++) {
                int kbase = kt2*32 + quad*8;
                bf16x8 pf = *(const bf16x8*)&Ps[wave][l16][kbase];
                #pragma unroll
                for (int t = 0; t < 8; t++) {
                    int d = t*16 + l16;
                    int colstart = (kbase + (((d>>3)&7) << 3)) & 63;
                    bf16x8 vf = *(const bf16x8*)&VsT[d*72 + colstart];
                    oacc[t] = MFMA16(pf, vf, oacc[t], 0, 0, 0);
                }
            }
        }

        // epilogue: normalize, stage to Os overlay, coalesced store
        __syncthreads();
        float inv[4];
        #pragma unroll
        for (int r = 0; r < 4; r++) inv[r] = 1.f / l_run[r];
        #pragma unroll
        for (int t = 0; t < 8; t++)
            #pragma unroll
            for (int r = 0; r < 4; r++)
                Os[(wave*16 + quad*4 + r)*136 + t*16 + l16] = bfbits(oacc[t][r]*inv[r]);
        __syncthreads();
        #pragma unroll
        for (int r4 = 0; r4 < 4; r4++) {
            int row = r4*4 + quad;
            uint4 val = *(const uint4*)&Os[(wave*16 + row)*136 + l16*8];
            size_t gaddr = base + (size_t)(i0 + wave*16 + row)*16384 + l16*8;
            *(uint4*)(o + gaddr) = val;
        }
    }
}

// ---------------------------------------------------------------------------
// FUSED variable attention + out-projection + residual.  One block per
// (bl,w).  Computes ov (MFMA vattn), osum = ov + ot (tattn output, coalesced
// read), then h += osum @ woutT^T + bias.  Eliminates o write+read round trip.
// ---------------------------------------------------------------------------
__global__ __launch_bounds__(256) void vproj_mfma(
    const bf16* __restrict__ q, const bf16* __restrict__ k, const bf16* __restrict__ v,
    const bf16* __restrict__ ot, const bf16* __restrict__ woT,
    const float* __restrict__ bo, float* __restrict__ h, int tokbase)
{
    __shared__ __align__(16) unsigned short VsT[1024*24];   // 49,152 B
    __shared__ __align__(16) unsigned short Ps[4][16][24];  //  3,072 B
    unsigned short* Osum = VsT;                              // [16][1040] = 33,280 B overlay

    int tid = threadIdx.x;
    int lane = tid & 63, wave = tid >> 6, quad = lane >> 4, l16 = lane & 15;
    size_t base = (size_t)blockIdx.x * 16384;

    // stage V^T for all heads: VsT[d][j] = V[j][d]
    #pragma unroll
    for (int p = 0; p < 8; p++) {
        int lin = p*256 + tid;
        int j = lin >> 7, d0 = (lin & 127)*8;
        union { uint4 u; unsigned short sh[8]; } uu;
        uu.u = *(const uint4*)(v + base + (size_t)j*1024 + d0);
        #pragma unroll
        for (int e = 0; e < 8; e++) VsT[(d0+e)*24 + j] = uu.sh[e];
    }
    __syncthreads();

    bf16x8 zf = {0,0,0,0,0,0,0,0};
    f32x4 oa[2][8];
    #pragma unroll
    for (int hi = 0; hi < 2; hi++) {
        int hh = wave*2 + hi;
        size_t hb = base + hh*128;

        f32x4 s = {0.f,0.f,0.f,0.f};
        #pragma unroll
        for (int kt = 0; kt < 4; kt++) {
            bf16x8 qf = *(const bf16x8*)(q + hb + (size_t)l16*1024 + kt*32 + quad*8);
            bf16x8 kf = *(const bf16x8*)(k + hb + (size_t)l16*1024 + kt*32 + quad*8);
            s = MFMA16(qf, kf, s, 0, 0, 0);
        }
        float p[4];
        #pragma unroll
        for (int r = 0; r < 4; r++) {
            float mxv = s[r];
            #pragma unroll
            for (int m = 1; m < 16; m <<= 1) mxv = fmaxf(mxv, __shfl_xor(mxv, m, 64));
            float e = __expf(s[r] - mxv);
            float smv = e;
            #pragma unroll
            for (int m = 1; m < 16; m <<= 1) smv += __shfl_xor(smv, m, 64);
            p[r] = e / smv;
        }
        #pragma unroll
        for (int r = 0; r < 4; r++) Ps[wave][quad*4+r][l16] = bfbits(p[r]);

        bf16x8 pf = zf;
        if (quad < 2) pf = *(const bf16x8*)&Ps[wave][l16][quad*8];
        #pragma unroll
        for (int dt = 0; dt < 8; dt++) oa[hi][dt] = 0.f;
        #pragma unroll
        for (int dt = 0; dt < 8; dt++) {
            bf16x8 vf = zf;
            if (quad < 2) vf = *(const bf16x8*)&VsT[(size_t)(hh*128 + dt*16 + l16)*24 + quad*8];
            oa[hi][dt] = MFMA16(pf, vf, oa[hi][dt], 0, 0, 0);
        }
    }

    // stage ov into Osum overlay (rows = f/token, cols = h*128+d)
    __syncthreads();   // all VsT reads done
    #pragma unroll
    for (int hi = 0; hi < 2; hi++) {
        int hh = wave*2 + hi;
        #pragma unroll
        for (int dt = 0; dt < 8; dt++)
            #pragma unroll
            for (int r = 0; r < 4; r++)
                Osum[(quad*4 + r)*1040 + hh*128 + dt*16 + l16] = bfbits(oa[hi][dt][r]);
    }
    __syncthreads();

    // osum += ot (coalesced global read of tattn output)
    #pragma unroll
    for (int u = 0; u < 8; u++) {
        int lin = u*256 + tid;
        int fr = lin >> 7, dc = (lin & 127)*8;
        union { uint4 u4; unsigned short sh[8]; } a, bsh, w;
        a.u4   = *(const uint4*)(ot + base + (size_t)fr*1024 + dc);
        bsh.u4 = *(const uint4*)&Osum[fr*1040 + dc];
        #pragma unroll
        for (int e = 0; e < 8; e++)
            w.sh[e] = bfbits(bits2f(a.sh[e]) + bits2f(bsh.sh[e]));
        *(uint4*)&Osum[fr*1040 + dc] = w.u4;
    }
    __syncthreads();

    // proj: C[16 tok][128] = Osum[16][1024] @ woT^T; wave owns 32 n-cols
    f32x4 pacc[2];
    pacc[0] = 0.f; pacc[1] = 0.f;
    #pragma unroll 4
    for (int kt2 = 0; kt2 < 32; kt2++) {
        bf16x8 af2 = *(const bf16x8*)&Osum[l16*1040 + kt2*32 + quad*8];
        #pragma unroll
        for (int nt = 0; nt < 2; nt++) {
            bf16x8 bfr = *(const bf16x8*)(woT + (size_t)(wave*32 + nt*16 + l16)*1024 + kt2*32 + quad*8);
            pacc[nt] = MFMA16(af2, bfr, pacc[nt], 0, 0, 0);
        }
    }

    // epilogue: h += C + bias (C rows = quad*4+r = token, col = l16)
    int htok = tokbase + blockIdx.x*16;
    #pragma unroll
    for (int nt = 0; nt < 2; nt++) {
        int n = wave*32 + nt*16 + l16;
        #pragma unroll
        for (int r = 0; r < 4; r++) {
            size_t idx = (size_t)(htok + quad*4 + r)*128 + n;
            h[idx] += pacc[nt][r] + bo[n];
        }
    }
}

// ---------------------------------------------------------------------------
// head, MFMA: out[2048,16] = h[2048,2048]@whT^T + bh
// ---------------------------------------------------------------------------
__global__ __launch_bounds__(256) void head_mfma(
    const float* __restrict__ h, const bf16* __restrict__ whT,
    const float* __restrict__ bh, float* __restrict__ out)
{
    __shared__ float sred[4][16][17];
    int tid = threadIdx.x;
    int lane = tid & 63, wave = tid >> 6, quad = lane >> 4, l16 = lane & 15;
    int bw0 = blockIdx.x * 16;
    const float* hrow = h + (size_t)(bw0 + l16)*2048 + wave*512;
    const bf16* wrow  = whT + (size_t)l16*2048 + wave*512;

    f32x4 acc = {0.f,0.f,0.f,0.f};
    #pragma unroll 4
    for (int kc = 0; kc < 16; kc++) {
        int ko = kc*32 + quad*8;
        float4 a0 = *(const float4*)(hrow + ko);
        float4 a1 = *(const float4*)(hrow + ko + 4);
        union { bf16x8 v; unsigned short sh[8]; } ua;
        ua.sh[0]=bfbits(a0.x); ua.sh[1]=bfbits(a0.y); ua.sh[2]=bfbits(a0.z); ua.sh[3]=bfbits(a0.w);
        ua.sh[4]=bfbits(a1.x); ua.sh[5]=bfbits(a1.y); ua.sh[6]=bfbits(a1.z); ua.sh[7]=bfbits(a1.w);
        bf16x8 bv = *(const bf16x8*)(wrow + ko);
        acc = MFMA16(ua.v, bv, acc, 0, 0, 0);
    }
    #pragma unroll
    for (int r = 0; r < 4; r++) sred[wave][quad*4+r][l16] = acc[r];
    __syncthreads();
    int i = tid >> 4, n = tid & 15;
    float s = bh[n] + sred[0][i][n] + sred[1][i][n] + sred[2][i][n] + sred[3][i][n];
    out[(size_t)(bw0 + i)*16 + n] = s;
}

// ---------------------------------------------------------------------------
extern "C" void kernel_launch(void* const* d_in, const int* in_sizes, int n_in,
                              void* d_out, int out_size, void* d_ws, size_t ws_size,
                              hipStream_t stream)
{
    const float* x    = (const float*)d_in[0];
    const float* w1   = (const float*)d_in[1];
    const float* b1   = (const float*)d_in[2];
    const float* w2   = (const float*)d_in[3];
    const float* b2   = (const float*)d_in[4];
    const float* w3   = (const float*)d_in[5];
    const float* b3   = (const float*)d_in[6];
    const float* wval = (const float*)d_in[7];
    const float* bval = (const float*)d_in[8];
    const float* lng  = (const float*)d_in[9];
    const float* lnb  = (const float*)d_in[10];
    const float* wqkv = (const float*)d_in[11];
    const float* wout = (const float*)d_in[12];
    const float* bout = (const float*)d_in[13];
    const float* wh   = (const float*)d_in[14];
    const float* bh   = (const float*)d_in[15];
    float* out = (float*)d_out;

    char* ws = (char*)d_ws;
    bf16*  wqkvT = (bf16*)ws;                       // 3,145,728 B
    bf16*  woutT = (bf16*)(ws + 3145728);           // 1,048,576 B
    bf16*  whT   = (bf16*)(ws + 4194304);           //    65,536 B
    float* h     = (float*)(ws + 4259840);          // 16,777,216 B
    bf16*  hn    = (bf16*)(ws + 21037056);          //  8,388,608 B
    const size_t qoff = 29425664ull;

    int NBL = 1;
    if      (ws_size >= qoff + 8ull*4ull*8388608ull) NBL = 8;
    else if (ws_size >= qoff + 4ull*4ull*8388608ull) NBL = 4;
    else if (ws_size >= qoff + 2ull*4ull*8388608ull) NBL = 2;
    size_t bsz = (size_t)NBL * 8388608ull;
    bf16* q  = (bf16*)(ws + qoff);
    bf16* kk = (bf16*)(ws + qoff + bsz);
    bf16* vv = (bf16*)(ws + qoff + 2*bsz);
    bf16* oo = (bf16*)(ws + qoff + 3*bsz);

    convert_w<<<8320, 256, 0, stream>>>(wqkv, wout, wh, wqkvT, woutT, whT);
    embed_kernel<<<BB*WW, 256, 0, stream>>>(x, w1,b1, w2,b2, w3,b3, wval, bval, h);

    for (int l = 0; l < 4; l++) {
        const bf16* wqT_l = wqkvT + (size_t)l*3072*128;
        const bf16* woT_l = woutT + (size_t)l*128*1024;
        const float* bo_l = bout + l*128;
        ln_kernel<<<NTOK/16, 256, 0, stream>>>(h, lng + l*128, lnb + l*128, hn);
        for (int bb = 0; bb < BB; bb += NBL) {
            int tokbase = bb*WW*FF;
            qkv_mfma<<<dim3(NBL*32, 24), 256, 0, stream>>>(
                hn, wqT_l, q, kk, vv, tokbase);
            tattn_mfma<<<NBL*FF*HH, 256, 0, stream>>>(q, kk, vv, oo);        // writes ot
            vproj_mfma<<<NBL*WW, 256, 0, stream>>>(q, kk, vv, oo, woT_l,
                                                   bo_l, h, tokbase);        // h += (ov+ot)@wo + b
        }
    }

    head_mfma<<<BB*WW/16, 256, 0, stream>>>(h, whT, bh, out);
}